// Round 1
// baseline (1030.905 us; speedup 1.0000x reference)
//
#include <hip/hip_runtime.h>
#include <cstddef>

#define BB 32
#define TT 64
#define NN_ 2048
#define SS 2048
#define DD 256
#define GG 1024

// ---------------- prep kernels ----------------

__global__ __launch_bounds__(256) void k_gather(const float* __restrict__ emb,
                                                const int* __restrict__ gt,
                                                const float* __restrict__ go,
                                                float* __restrict__ x) {
    int idx = blockIdx.x * 256 + threadIdx.x;     // over B*T*D = 524288
    int d = idx & (DD - 1);
    int t = (idx >> 8) & (TT - 1);
    int b = idx >> 14;
    float v;
    if (t == 0) v = go[d];
    else        v = emb[((size_t)b * NN_ + gt[b * TT + t - 1]) * DD + d];
    x[idx] = v;
}

// WhhT2[(k*256 + j)*4 + g] = Whh[(g*256 + j)*256 + k]
__global__ __launch_bounds__(256) void k_whht(const float* __restrict__ Whh,
                                              float* __restrict__ WhhT2) {
    int idx = blockIdx.x * 256 + threadIdx.x;     // over D*G = 262144
    int g = idx & 3;
    int j = (idx >> 2) & 255;
    int k = idx >> 10;
    WhhT2[idx] = Whh[(size_t)((g << 8) + j) * DD + k];
}

__global__ __launch_bounds__(256) void k_first_init(int* __restrict__ firstpos) {
    int idx = blockIdx.x * 256 + threadIdx.x;     // B*N
    firstpos[idx] = TT;                            // "never picked"
}

__global__ __launch_bounds__(256) void k_first_min(const int* __restrict__ gt,
                                                   int* __restrict__ firstpos) {
    int idx = blockIdx.x * 256 + threadIdx.x;     // B*T = 2048
    int b = idx / TT;
    int t = idx % TT;
    atomicMin(&firstpos[(size_t)b * NN_ + gt[idx]], t);
}

// ---------------- generic tiled f32 GEMMs ----------------
// gemm_nt: C[m,n] = sum_k A[m*lda+k] * Bm[n*ldb+k] (+bias1[n]+bias2[n])
__global__ __launch_bounds__(256) void gemm_nt(const float* __restrict__ A,
                                               const float* __restrict__ Bm,
                                               float* __restrict__ C,
                                               int K, int lda, int ldb, int ldc,
                                               long sA, long sB, long sC,
                                               const float* __restrict__ bias1,
                                               const float* __restrict__ bias2) {
    int bz = blockIdx.z;
    A += (size_t)bz * sA; Bm += (size_t)bz * sB; C += (size_t)bz * sC;
    int tm = blockIdx.y * 64, tn = blockIdx.x * 64;
    __shared__ float As[16][65];
    __shared__ float Bs[16][65];
    int tid = threadIdx.x;
    int tx = tid & 15, ty = tid >> 4;
    float acc[4][4] = {};
    for (int k0 = 0; k0 < K; k0 += 16) {
#pragma unroll
        for (int i = 0; i < 4; ++i) {
            As[tx][ty + 16 * i] = A[(size_t)(tm + ty + 16 * i) * lda + k0 + tx];
            Bs[tx][ty + 16 * i] = Bm[(size_t)(tn + ty + 16 * i) * ldb + k0 + tx];
        }
        __syncthreads();
#pragma unroll
        for (int k = 0; k < 16; ++k) {
            float av[4], bv[4];
#pragma unroll
            for (int i = 0; i < 4; ++i) { av[i] = As[k][ty * 4 + i]; bv[i] = Bs[k][tx * 4 + i]; }
#pragma unroll
            for (int i = 0; i < 4; ++i)
#pragma unroll
                for (int j = 0; j < 4; ++j) acc[i][j] += av[i] * bv[j];
        }
        __syncthreads();
    }
#pragma unroll
    for (int i = 0; i < 4; ++i) {
        int m = tm + ty * 4 + i;
#pragma unroll
        for (int j = 0; j < 4; ++j) {
            int n = tn + tx * 4 + j;
            float v = acc[i][j];
            if (bias1) v += bias1[n];
            if (bias2) v += bias2[n];
            C[(size_t)m * ldc + n] = v;
        }
    }
}

// gemm_nn: C[m,n] = sum_k A[m*lda+k] * Bm[k*ldb+n]
__global__ __launch_bounds__(256) void gemm_nn(const float* __restrict__ A,
                                               const float* __restrict__ Bm,
                                               float* __restrict__ C,
                                               int K, int lda, int ldb, int ldc,
                                               long sA, long sB, long sC) {
    int bz = blockIdx.z;
    A += (size_t)bz * sA; Bm += (size_t)bz * sB; C += (size_t)bz * sC;
    int tm = blockIdx.y * 64, tn = blockIdx.x * 64;
    __shared__ float As[16][65];
    __shared__ float Bs[16][65];
    int tid = threadIdx.x;
    int tx = tid & 15, ty = tid >> 4;
    float acc[4][4] = {};
    for (int k0 = 0; k0 < K; k0 += 16) {
#pragma unroll
        for (int i = 0; i < 4; ++i)
            As[tx][ty + 16 * i] = A[(size_t)(tm + ty + 16 * i) * lda + k0 + tx];
#pragma unroll
        for (int i = 0; i < 4; ++i)
            Bs[(tid >> 6) + 4 * i][tid & 63] =
                Bm[(size_t)(k0 + (tid >> 6) + 4 * i) * ldb + tn + (tid & 63)];
        __syncthreads();
#pragma unroll
        for (int k = 0; k < 16; ++k) {
            float av[4], bv[4];
#pragma unroll
            for (int i = 0; i < 4; ++i) { av[i] = As[k][ty * 4 + i]; bv[i] = Bs[k][tx * 4 + i]; }
#pragma unroll
            for (int i = 0; i < 4; ++i)
#pragma unroll
                for (int j = 0; j < 4; ++j) acc[i][j] += av[i] * bv[j];
        }
        __syncthreads();
    }
#pragma unroll
    for (int i = 0; i < 4; ++i) {
        int m = tm + ty * 4 + i;
#pragma unroll
        for (int j = 0; j < 4; ++j)
            C[(size_t)m * ldc + (tn + tx * 4 + j)] = acc[i][j];
    }
}

// score GEMM: M=64 (t), N tile 64 (n), K=256. Epilogue adds picked/mask terms.
__global__ __launch_bounds__(256) void gemm_score(const float* __restrict__ A,   // feat [T,257]
                                                  const float* __restrict__ Bm,  // emb  [N,256]
                                                  float* __restrict__ C,         // out  [T,N]
                                                  const int* __restrict__ firstpos,
                                                  const float* __restrict__ emb_mask,
                                                  int lda, int ldb, int ldc,
                                                  long sA, long sB, long sC) {
    int b = blockIdx.z;
    A += (size_t)b * sA; Bm += (size_t)b * sB; C += (size_t)b * sC;
    int tn = blockIdx.x * 64;
    __shared__ float As[16][65];
    __shared__ float Bs[16][65];
    int tid = threadIdx.x;
    int tx = tid & 15, ty = tid >> 4;
    float acc[4][4] = {};
    for (int k0 = 0; k0 < DD; k0 += 16) {
#pragma unroll
        for (int i = 0; i < 4; ++i) {
            As[tx][ty + 16 * i] = A[(size_t)(ty + 16 * i) * lda + k0 + tx];
            Bs[tx][ty + 16 * i] = Bm[(size_t)(tn + ty + 16 * i) * ldb + k0 + tx];
        }
        __syncthreads();
#pragma unroll
        for (int k = 0; k < 16; ++k) {
            float av[4], bv[4];
#pragma unroll
            for (int i = 0; i < 4; ++i) { av[i] = As[k][ty * 4 + i]; bv[i] = Bs[k][tx * 4 + i]; }
#pragma unroll
            for (int i = 0; i < 4; ++i)
#pragma unroll
                for (int j = 0; j < 4; ++j) acc[i][j] += av[i] * bv[j];
        }
        __syncthreads();
    }
#pragma unroll
    for (int i = 0; i < 4; ++i) {
        int t = ty * 4 + i;
        float fs = A[(size_t)t * lda + 256];   // feat[..., -1]
#pragma unroll
        for (int j = 0; j < 4; ++j) {
            int n = tn + tx * 4 + j;
            float v = acc[i][j];
            if (firstpos[(size_t)b * NN_ + n] < t) v += fs;
            v -= (1.0f - emb_mask[(size_t)b * NN_ + n]) * 1e20f;
            C[(size_t)t * ldc + n] = v;
        }
    }
}

// ---------------- LSTM ----------------
// one block per batch element, thread j owns hidden unit j (c in register).
__global__ __launch_bounds__(256) void k_lstm(const float* __restrict__ xW,
                                              const float* __restrict__ WhhT2,
                                              float* __restrict__ hs) {
    int b = blockIdx.x;
    int j = threadIdx.x;
    __shared__ float h_lds[DD];
    float c = 0.0f;
    h_lds[j] = 0.0f;
    __syncthreads();
    const float4* Wt = (const float4*)WhhT2;   // Wt[k*256 + j] = {wi,wf,wg,wo}
    for (int t = 0; t < TT; ++t) {
        const float* g0 = xW + (size_t)(b * TT + t) * GG;
        float ai = g0[j], af = g0[DD + j], ag = g0[2 * DD + j], ao = g0[3 * DD + j];
#pragma unroll 8
        for (int k = 0; k < DD; ++k) {
            float hk = h_lds[k];
            float4 w4 = Wt[k * DD + j];
            ai += hk * w4.x;
            af += hk * w4.y;
            ag += hk * w4.z;
            ao += hk * w4.w;
        }
        float ig = 1.0f / (1.0f + __expf(-ai));
        float fg = 1.0f / (1.0f + __expf(-af));
        float gg = tanhf(ag);
        float og = 1.0f / (1.0f + __expf(-ao));
        c = fg * c + ig * gg;
        float hn = og * tanhf(c);
        __syncthreads();                  // all reads of h_lds done
        h_lds[j] = hn;
        hs[(size_t)(b * TT + t) * DD + j] = hn;
        __syncthreads();
    }
}

// ---------------- softmax over S (in place, masked) ----------------
__global__ __launch_bounds__(256) void k_softmax(float* __restrict__ raw,
                                                 const float* __restrict__ enc_mask) {
    int bt = blockIdx.x;
    int b = bt / TT;
    float* r = raw + (size_t)bt * SS;
    __shared__ float row[SS];
    __shared__ float red[16];
    int tid = threadIdx.x;
    float mx = -1e30f;
    for (int s = tid; s < SS; s += 256) {
        float v = r[s] - (1.0f - enc_mask[(size_t)b * SS + s]) * 1e20f;
        row[s] = v;
        mx = fmaxf(mx, v);
    }
#pragma unroll
    for (int o = 32; o > 0; o >>= 1) mx = fmaxf(mx, __shfl_down(mx, o));
    if ((tid & 63) == 0) red[tid >> 6] = mx;
    __syncthreads();
    if (tid == 0) {
        float m = red[0];
        for (int i = 1; i < 4; ++i) m = fmaxf(m, red[i]);
        red[0] = m;
    }
    __syncthreads();
    mx = red[0];
    float sum = 0.0f;
    for (int s = tid; s < SS; s += 256) {
        float e = expf(row[s] - mx);
        row[s] = e;
        sum += e;
    }
#pragma unroll
    for (int o = 32; o > 0; o >>= 1) sum += __shfl_down(sum, o);
    if ((tid & 63) == 0) red[8 + (tid >> 6)] = sum;
    __syncthreads();
    if (tid == 0) {
        float s = red[8];
        for (int i = 1; i < 4; ++i) s += red[8 + i];
        red[8] = s;
    }
    __syncthreads();
    float inv = 1.0f / red[8];
    for (int s = tid; s < SS; s += 256) r[s] = row[s] * inv;
}

// ---------------- feat = [hs|attn] @ Wf^T + bf ----------------
__global__ __launch_bounds__(256) void k_feat(const float* __restrict__ hs,
                                              const float* __restrict__ attn,
                                              const float* __restrict__ Wf,
                                              const float* __restrict__ bf,
                                              float* __restrict__ feat) {
    int bt = blockIdx.x;
    __shared__ float cat[2 * DD];
    int tid = threadIdx.x;
    cat[tid] = hs[(size_t)bt * DD + tid];
    cat[DD + tid] = attn[(size_t)bt * DD + tid];
    __syncthreads();
    for (int n = tid; n < DD + 1; n += 256) {
        float s = bf[n];
        const float* w = Wf + (size_t)n * (2 * DD);
#pragma unroll 4
        for (int k = 0; k < 2 * DD; ++k) s += cat[k] * w[k];
        feat[(size_t)bt * 257 + n] = s;
    }
}

// ---------------- launch ----------------
extern "C" void kernel_launch(void* const* d_in, const int* in_sizes, int n_in,
                              void* d_out, int out_size, void* d_ws, size_t ws_size,
                              hipStream_t stream) {
    const float* emb      = (const float*)d_in[0];
    const float* emb_mask = (const float*)d_in[1];
    const float* enc      = (const float*)d_in[2];
    const float* enc_mask = (const float*)d_in[3];
    const int*   gt       = (const int*)d_in[4];
    const float* go       = (const float*)d_in[5];
    const float* Wih      = (const float*)d_in[6];
    const float* Whh      = (const float*)d_in[7];
    const float* bih      = (const float*)d_in[8];
    const float* bhh      = (const float*)d_in[9];
    const float* Wdt      = (const float*)d_in[10];
    const float* bdt      = (const float*)d_in[11];
    const float* Wf       = (const float*)d_in[12];
    const float* bf       = (const float*)d_in[13];
    float* out = (float*)d_out;

    float* ws    = (float*)d_ws;
    float* x     = ws;                                   // [B*T*D]
    float* xW    = x     + (size_t)BB * TT * DD;         // [B*T*G]
    float* WhhT2 = xW    + (size_t)BB * TT * GG;         // [D*G]
    float* hs    = WhhT2 + (size_t)DD * GG;              // [B*T*D]
    float* dec   = hs    + (size_t)BB * TT * DD;         // [B*T*D]
    float* w     = dec   + (size_t)BB * TT * DD;         // [B*T*S]
    float* attn  = w     + (size_t)BB * TT * SS;         // [B*T*D]
    float* feat  = attn  + (size_t)BB * TT * DD;         // [B*T*257]
    int* firstpos = (int*)(feat + (size_t)BB * TT * 257);// [B*N]

    k_gather<<<BB * TT * DD / 256, 256, 0, stream>>>(emb, gt, go, x);
    k_whht<<<DD * GG / 256, 256, 0, stream>>>(Whh, WhhT2);
    k_first_init<<<BB * NN_ / 256, 256, 0, stream>>>(firstpos);
    k_first_min<<<BB * TT / 256, 256, 0, stream>>>(gt, firstpos);

    // xW = x @ Wih^T + bih + bhh : [2048,1024] = [2048,256]x[1024,256]^T
    gemm_nt<<<dim3(GG / 64, BB * TT / 64, 1), 256, 0, stream>>>(
        x, Wih, xW, DD, DD, DD, GG, 0, 0, 0, bih, bhh);

    k_lstm<<<BB, 256, 0, stream>>>(xW, WhhT2, hs);

    // dec = hs @ Wdt^T + bdt : [2048,256]
    gemm_nt<<<dim3(DD / 64, BB * TT / 64, 1), 256, 0, stream>>>(
        hs, Wdt, dec, DD, DD, DD, DD, 0, 0, 0, bdt, nullptr);

    // raw[b] = dec[b] @ enc[b]^T : [64,2048], batch 32
    gemm_nt<<<dim3(SS / 64, TT / 64, BB), 256, 0, stream>>>(
        dec, enc, w, DD, DD, DD, SS,
        (long)TT * DD, (long)SS * DD, (long)TT * SS, nullptr, nullptr);

    k_softmax<<<BB * TT, 256, 0, stream>>>(w, enc_mask);

    // attn[b] = w[b] @ enc[b] : [64,256], batch 32
    gemm_nn<<<dim3(DD / 64, TT / 64, BB), 256, 0, stream>>>(
        w, enc, attn, SS, SS, DD, DD,
        (long)TT * SS, (long)SS * DD, (long)TT * DD);

    k_feat<<<BB * TT, 256, 0, stream>>>(hs, attn, Wf, bf, feat);

    // score[b] = feat[b,:, :256] @ emb[b]^T (+ picked, mask)
    gemm_score<<<dim3(NN_ / 64, TT / 64, BB), 256, 0, stream>>>(
        feat, emb, out, firstpos, emb_mask,
        257, DD, NN_, (long)TT * 257, (long)NN_ * DD, (long)TT * NN_);
}

// Round 2
// 937.031 us; speedup vs baseline: 1.1002x; 1.1002x over previous
//
#include <hip/hip_runtime.h>
#include <cstddef>

#define BB 32
#define TT 64
#define NN_ 2048
#define SS 2048
#define DD 256
#define GG 1024
#define LP 32   // LSTM blocks (col-slices)

typedef __attribute__((ext_vector_type(8))) short short8;
typedef __attribute__((ext_vector_type(4))) float f32x4;

static __device__ inline unsigned short f2bf(float f) {
    union { float f; unsigned int u; } v; v.f = f;
    unsigned int u = v.u;
    unsigned int r = u + 0x7FFF + ((u >> 16) & 1);   // RNE
    return (unsigned short)(r >> 16);
}

// ---------------- prep kernels ----------------

__global__ __launch_bounds__(256) void k_gather(const float* __restrict__ emb,
                                                const int* __restrict__ gt,
                                                const float* __restrict__ go,
                                                float* __restrict__ x) {
    int idx = blockIdx.x * 256 + threadIdx.x;     // over B*T*D = 524288
    int d = idx & (DD - 1);
    int t = (idx >> 8) & (TT - 1);
    int b = idx >> 14;
    float v;
    if (t == 0) v = go[d];
    else        v = emb[((size_t)b * NN_ + gt[b * TT + t - 1]) * DD + d];
    x[idx] = v;
}

__global__ __launch_bounds__(256) void k_first_init(int* __restrict__ firstpos) {
    int idx = blockIdx.x * 256 + threadIdx.x;     // B*N
    firstpos[idx] = TT;                            // "never picked"
}

__global__ __launch_bounds__(256) void k_first_min(const int* __restrict__ gt,
                                                   int* __restrict__ firstpos) {
    int idx = blockIdx.x * 256 + threadIdx.x;     // B*T = 2048
    int b = idx / TT;
    int t = idx % TT;
    atomicMin(&firstpos[(size_t)b * NN_ + gt[idx]], t);
}

__global__ __launch_bounds__(64) void k_zero_flags(int* __restrict__ flags) {
    flags[threadIdx.x] = 0;
}

// ---------------- generic tiled f32 GEMMs ----------------
__global__ __launch_bounds__(256) void gemm_nt(const float* __restrict__ A,
                                               const float* __restrict__ Bm,
                                               float* __restrict__ C,
                                               int K, int lda, int ldb, int ldc,
                                               long sA, long sB, long sC,
                                               const float* __restrict__ bias1,
                                               const float* __restrict__ bias2) {
    int bz = blockIdx.z;
    A += (size_t)bz * sA; Bm += (size_t)bz * sB; C += (size_t)bz * sC;
    int tm = blockIdx.y * 64, tn = blockIdx.x * 64;
    __shared__ float As[16][65];
    __shared__ float Bs[16][65];
    int tid = threadIdx.x;
    int tx = tid & 15, ty = tid >> 4;
    float acc[4][4] = {};
    for (int k0 = 0; k0 < K; k0 += 16) {
#pragma unroll
        for (int i = 0; i < 4; ++i) {
            As[tx][ty + 16 * i] = A[(size_t)(tm + ty + 16 * i) * lda + k0 + tx];
            Bs[tx][ty + 16 * i] = Bm[(size_t)(tn + ty + 16 * i) * ldb + k0 + tx];
        }
        __syncthreads();
#pragma unroll
        for (int k = 0; k < 16; ++k) {
            float av[4], bv[4];
#pragma unroll
            for (int i = 0; i < 4; ++i) { av[i] = As[k][ty * 4 + i]; bv[i] = Bs[k][tx * 4 + i]; }
#pragma unroll
            for (int i = 0; i < 4; ++i)
#pragma unroll
                for (int j = 0; j < 4; ++j) acc[i][j] += av[i] * bv[j];
        }
        __syncthreads();
    }
#pragma unroll
    for (int i = 0; i < 4; ++i) {
        int m = tm + ty * 4 + i;
#pragma unroll
        for (int j = 0; j < 4; ++j) {
            int n = tn + tx * 4 + j;
            float v = acc[i][j];
            if (bias1) v += bias1[n];
            if (bias2) v += bias2[n];
            C[(size_t)m * ldc + n] = v;
        }
    }
}

__global__ __launch_bounds__(256) void gemm_nn(const float* __restrict__ A,
                                               const float* __restrict__ Bm,
                                               float* __restrict__ C,
                                               int K, int lda, int ldb, int ldc,
                                               long sA, long sB, long sC) {
    int bz = blockIdx.z;
    A += (size_t)bz * sA; Bm += (size_t)bz * sB; C += (size_t)bz * sC;
    int tm = blockIdx.y * 64, tn = blockIdx.x * 64;
    __shared__ float As[16][65];
    __shared__ float Bs[16][65];
    int tid = threadIdx.x;
    int tx = tid & 15, ty = tid >> 4;
    float acc[4][4] = {};
    for (int k0 = 0; k0 < K; k0 += 16) {
#pragma unroll
        for (int i = 0; i < 4; ++i)
            As[tx][ty + 16 * i] = A[(size_t)(tm + ty + 16 * i) * lda + k0 + tx];
#pragma unroll
        for (int i = 0; i < 4; ++i)
            Bs[(tid >> 6) + 4 * i][tid & 63] =
                Bm[(size_t)(k0 + (tid >> 6) + 4 * i) * ldb + tn + (tid & 63)];
        __syncthreads();
#pragma unroll
        for (int k = 0; k < 16; ++k) {
            float av[4], bv[4];
#pragma unroll
            for (int i = 0; i < 4; ++i) { av[i] = As[k][ty * 4 + i]; bv[i] = Bs[k][tx * 4 + i]; }
#pragma unroll
            for (int i = 0; i < 4; ++i)
#pragma unroll
                for (int j = 0; j < 4; ++j) acc[i][j] += av[i] * bv[j];
        }
        __syncthreads();
    }
#pragma unroll
    for (int i = 0; i < 4; ++i) {
        int m = tm + ty * 4 + i;
#pragma unroll
        for (int j = 0; j < 4; ++j)
            C[(size_t)m * ldc + (tn + tx * 4 + j)] = acc[i][j];
    }
}

__global__ __launch_bounds__(256) void gemm_score(const float* __restrict__ A,   // feat [T,257]
                                                  const float* __restrict__ Bm,  // emb  [N,256]
                                                  float* __restrict__ C,         // out  [T,N]
                                                  const int* __restrict__ firstpos,
                                                  const float* __restrict__ emb_mask,
                                                  int lda, int ldb, int ldc,
                                                  long sA, long sB, long sC) {
    int b = blockIdx.z;
    A += (size_t)b * sA; Bm += (size_t)b * sB; C += (size_t)b * sC;
    int tn = blockIdx.x * 64;
    __shared__ float As[16][65];
    __shared__ float Bs[16][65];
    int tid = threadIdx.x;
    int tx = tid & 15, ty = tid >> 4;
    float acc[4][4] = {};
    for (int k0 = 0; k0 < DD; k0 += 16) {
#pragma unroll
        for (int i = 0; i < 4; ++i) {
            As[tx][ty + 16 * i] = A[(size_t)(ty + 16 * i) * lda + k0 + tx];
            Bs[tx][ty + 16 * i] = Bm[(size_t)(tn + ty + 16 * i) * ldb + k0 + tx];
        }
        __syncthreads();
#pragma unroll
        for (int k = 0; k < 16; ++k) {
            float av[4], bv[4];
#pragma unroll
            for (int i = 0; i < 4; ++i) { av[i] = As[k][ty * 4 + i]; bv[i] = Bs[k][tx * 4 + i]; }
#pragma unroll
            for (int i = 0; i < 4; ++i)
#pragma unroll
                for (int j = 0; j < 4; ++j) acc[i][j] += av[i] * bv[j];
        }
        __syncthreads();
    }
#pragma unroll
    for (int i = 0; i < 4; ++i) {
        int t = ty * 4 + i;
        float fs = A[(size_t)t * lda + 256];   // feat[..., -1]
#pragma unroll
        for (int j = 0; j < 4; ++j) {
            int n = tn + tx * 4 + j;
            float v = acc[i][j];
            if (firstpos[(size_t)b * NN_ + n] < t) v += fs;
            v -= (1.0f - emb_mask[(size_t)b * NN_ + n]) * 1e20f;
            C[(size_t)t * ldc + n] = v;
        }
    }
}

// ---------------- LSTM: 32 cooperating blocks, register-resident weights ----
// Block p owns 8 hidden units j = p*8..p*8+7 (=> 32 gate columns, col = g*8+jj).
// Weights live as persistent bf16 MFMA B-fragments (loaded once).
// Per step: [32b x 256k] @ [256k x 32col] via 8x mfma 16x16x32 per wave.
// h exchanged through global hbuf in MFMA-A-fragment layout (no staging on read).
__global__ __launch_bounds__(256) void k_lstm_mfma(const float* __restrict__ xW,
                                                   const float* __restrict__ Whh,
                                                   float* __restrict__ hs,
                                                   unsigned short* __restrict__ hbuf,
                                                   int* __restrict__ flags) {
    int p = blockIdx.x;            // 0..31 col-slice
    int tid = threadIdx.x;
    int lane = tid & 63;
    int wid = tid >> 6;            // 4 waves
    int m = wid & 1;               // M-tile (batches 16m..16m+15)
    int n = wid >> 1;              // N-tile (cols 16n..16n+15)

    // ---- persistent weight B-frags: bfrag[kt], lane holds col=16n+(lane&15),
    //      k = kt*32 + (lane>>4)*8 + e
    short8 bfrag[8];
    {
        int col = n * 16 + (lane & 15);        // 0..31
        int g = col >> 3, jj = col & 7;
        const float* wrow = Whh + (size_t)(g * 256 + p * 8 + jj) * DD;
#pragma unroll
        for (int kt = 0; kt < 8; ++kt) {
            short8 f;
#pragma unroll
            for (int e = 0; e < 8; ++e)
                f[e] = (short)f2bf(wrow[kt * 32 + (lane >> 4) * 8 + e]);
            bfrag[kt] = f;
        }
    }

    int ab = tid >> 3;             // activation thread: batch 0..31
    int aj = tid & 7;              // hidden unit jj 0..7
    int j = p * 8 + aj;
    float cstate = 0.0f;

    __shared__ float preact[32][33];

    for (int t = 0; t < TT; ++t) {
        // xW gate biases (independent of flags — issue early)
        const float* g0 = xW + ((size_t)ab * TT + t) * GG;
        float xi = g0[j], xf = g0[256 + j], xg = g0[512 + j], xo = g0[768 + j];

        f32x4 acc = {0.f, 0.f, 0.f, 0.f};
        if (t > 0) {
            if (tid == 0) {
                while (__hip_atomic_load(&flags[t - 1], __ATOMIC_ACQUIRE,
                                         __HIP_MEMORY_SCOPE_AGENT) < LP) { }
            }
            __syncthreads();
            const short* hb = (const short*)hbuf + ((size_t)(t - 1) * 2 + m) * 8 * 512;
#pragma unroll
            for (int kt = 0; kt < 8; ++kt) {
                short8 af = *(const short8*)(hb + (kt * 64 + lane) * 8);
                acc = __builtin_amdgcn_mfma_f32_16x16x32_bf16(af, bfrag[kt], acc, 0, 0, 0);
            }
        }
        // stage preacts: C layout col=lane&15, row=(lane>>4)*4+r
#pragma unroll
        for (int r = 0; r < 4; ++r)
            preact[16 * m + (lane >> 4) * 4 + r][n * 16 + (lane & 15)] = acc[r];
        __syncthreads();

        // activation: thread (ab, aj)
        float pi = xi + preact[ab][aj];
        float pf = xf + preact[ab][8 + aj];
        float pg = xg + preact[ab][16 + aj];
        float po = xo + preact[ab][24 + aj];
        float ig = 1.0f / (1.0f + __expf(-pi));
        float fg = 1.0f / (1.0f + __expf(-pf));
        float gg = tanhf(pg);
        float og = 1.0f / (1.0f + __expf(-po));
        cstate = fg * cstate + ig * gg;
        float hn = og * tanhf(cstate);

        hs[((size_t)ab * TT + t) * DD + j] = hn;
        // publish h in A-frag layout: value (b=ab, k=j) of step t
        hbuf[((size_t)t * 2 + (ab >> 4)) * 4096 +
             (size_t)(j >> 5) * 512 + (((j & 31) >> 3) * 16 + (ab & 15)) * 8 + (j & 7)]
            = f2bf(hn);

        __syncthreads();           // preact reuse + all writes issued
        __threadfence();
        if (tid == 0)
            __hip_atomic_fetch_add(&flags[t], 1, __ATOMIC_RELEASE, __HIP_MEMORY_SCOPE_AGENT);
    }
}

// ---------------- softmax over S (in place, masked) ----------------
__global__ __launch_bounds__(256) void k_softmax(float* __restrict__ raw,
                                                 const float* __restrict__ enc_mask) {
    int bt = blockIdx.x;
    int b = bt / TT;
    float* r = raw + (size_t)bt * SS;
    __shared__ float row[SS];
    __shared__ float red[16];
    int tid = threadIdx.x;
    float mx = -1e30f;
    for (int s = tid; s < SS; s += 256) {
        float v = r[s] - (1.0f - enc_mask[(size_t)b * SS + s]) * 1e20f;
        row[s] = v;
        mx = fmaxf(mx, v);
    }
#pragma unroll
    for (int o = 32; o > 0; o >>= 1) mx = fmaxf(mx, __shfl_down(mx, o));
    if ((tid & 63) == 0) red[tid >> 6] = mx;
    __syncthreads();
    if (tid == 0) {
        float m2 = red[0];
        for (int i = 1; i < 4; ++i) m2 = fmaxf(m2, red[i]);
        red[0] = m2;
    }
    __syncthreads();
    mx = red[0];
    float sum = 0.0f;
    for (int s = tid; s < SS; s += 256) {
        float e = expf(row[s] - mx);
        row[s] = e;
        sum += e;
    }
#pragma unroll
    for (int o = 32; o > 0; o >>= 1) sum += __shfl_down(sum, o);
    if ((tid & 63) == 0) red[8 + (tid >> 6)] = sum;
    __syncthreads();
    if (tid == 0) {
        float s = red[8];
        for (int i = 1; i < 4; ++i) s += red[8 + i];
        red[8] = s;
    }
    __syncthreads();
    float inv = 1.0f / red[8];
    for (int s = tid; s < SS; s += 256) r[s] = row[s] * inv;
}

// ---------------- feat = [hs|attn] @ Wf^T + bf ----------------
__global__ __launch_bounds__(256) void k_feat(const float* __restrict__ hs,
                                              const float* __restrict__ attn,
                                              const float* __restrict__ Wf,
                                              const float* __restrict__ bf,
                                              float* __restrict__ feat) {
    int bt = blockIdx.x;
    __shared__ float cat[2 * DD];
    int tid = threadIdx.x;
    cat[tid] = hs[(size_t)bt * DD + tid];
    cat[DD + tid] = attn[(size_t)bt * DD + tid];
    __syncthreads();
    for (int nn = tid; nn < DD + 1; nn += 256) {
        float s = bf[nn];
        const float* w = Wf + (size_t)nn * (2 * DD);
#pragma unroll 4
        for (int k = 0; k < 2 * DD; ++k) s += cat[k] * w[k];
        feat[(size_t)bt * 257 + nn] = s;
    }
}

// ---------------- launch ----------------
extern "C" void kernel_launch(void* const* d_in, const int* in_sizes, int n_in,
                              void* d_out, int out_size, void* d_ws, size_t ws_size,
                              hipStream_t stream) {
    const float* emb      = (const float*)d_in[0];
    const float* emb_mask = (const float*)d_in[1];
    const float* enc      = (const float*)d_in[2];
    const float* enc_mask = (const float*)d_in[3];
    const int*   gt       = (const int*)d_in[4];
    const float* go       = (const float*)d_in[5];
    const float* Wih      = (const float*)d_in[6];
    const float* Whh      = (const float*)d_in[7];
    const float* bih      = (const float*)d_in[8];
    const float* bhh      = (const float*)d_in[9];
    const float* Wdt      = (const float*)d_in[10];
    const float* bdt      = (const float*)d_in[11];
    const float* Wf       = (const float*)d_in[12];
    const float* bf       = (const float*)d_in[13];
    float* out = (float*)d_out;

    float* ws    = (float*)d_ws;
    float* x     = ws;                                   // [B*T*D]
    float* xW    = x     + (size_t)BB * TT * DD;         // [B*T*G]
    float* hs    = xW    + (size_t)BB * TT * GG;         // [B*T*D]
    float* dec   = hs    + (size_t)BB * TT * DD;         // [B*T*D]
    float* w     = dec   + (size_t)BB * TT * DD;         // [B*T*S]
    float* attn  = w     + (size_t)BB * TT * SS;         // [B*T*D]
    float* feat  = attn  + (size_t)BB * TT * DD;         // [B*T*257]
    float* feat_end = feat + (size_t)BB * TT * 257;
    int* firstpos = (int*)feat_end;                      // [B*N]
    int* flags    = firstpos + (size_t)BB * NN_;         // [T]
    unsigned short* hbuf = (unsigned short*)(flags + 64);// [T*2*8*64*8] bf16 (1MB)

    k_gather<<<BB * TT * DD / 256, 256, 0, stream>>>(emb, gt, go, x);
    k_first_init<<<BB * NN_ / 256, 256, 0, stream>>>(firstpos);
    k_first_min<<<BB * TT / 256, 256, 0, stream>>>(gt, firstpos);
    k_zero_flags<<<1, 64, 0, stream>>>(flags);

    // xW = x @ Wih^T + bih + bhh : [2048,1024]
    gemm_nt<<<dim3(GG / 64, BB * TT / 64, 1), 256, 0, stream>>>(
        x, Wih, xW, DD, DD, DD, GG, 0, 0, 0, bih, bhh);

    k_lstm_mfma<<<LP, 256, 0, stream>>>(xW, Whh, hs, hbuf, flags);

    // dec = hs @ Wdt^T + bdt : [2048,256]
    gemm_nt<<<dim3(DD / 64, BB * TT / 64, 1), 256, 0, stream>>>(
        hs, Wdt, dec, DD, DD, DD, DD, 0, 0, 0, bdt, nullptr);

    // raw[b] = dec[b] @ enc[b]^T : [64,2048], batch 32
    gemm_nt<<<dim3(SS / 64, TT / 64, BB), 256, 0, stream>>>(
        dec, enc, w, DD, DD, DD, SS,
        (long)TT * DD, (long)SS * DD, (long)TT * SS, nullptr, nullptr);

    k_softmax<<<BB * TT, 256, 0, stream>>>(w, enc_mask);

    // attn[b] = w[b] @ enc[b] : [64,256], batch 32
    gemm_nn<<<dim3(DD / 64, TT / 64, BB), 256, 0, stream>>>(
        w, enc, attn, SS, SS, DD, DD,
        (long)TT * SS, (long)SS * DD, (long)TT * DD);

    k_feat<<<BB * TT, 256, 0, stream>>>(hs, attn, Wf, bf, feat);

    // score[b] = feat[b,:, :256] @ emb[b]^T (+ picked, mask)
    gemm_score<<<dim3(NN_ / 64, TT / 64, BB), 256, 0, stream>>>(
        feat, emb, out, firstpos, emb_mask,
        257, DD, NN_, (long)TT * 257, (long)NN_ * DD, (long)TT * NN_);
}

// Round 3
// 722.342 us; speedup vs baseline: 1.4272x; 1.2972x over previous
//
#include <hip/hip_runtime.h>
#include <cstddef>

#define BB 32
#define TT 64
#define NN_ 2048
#define SS 2048
#define DD 256
#define GG 1024
#define LP 32   // LSTM blocks (col-slices)

typedef __attribute__((ext_vector_type(8))) short short8;
typedef __attribute__((ext_vector_type(4))) float f32x4;

static __device__ inline unsigned short f2bf(float f) {
    union { float f; unsigned int u; } v; v.f = f;
    unsigned int u = v.u;
    unsigned int r = u + 0x7FFF + ((u >> 16) & 1);   // RNE
    return (unsigned short)(r >> 16);
}

// ---------------- prep kernels ----------------

__global__ __launch_bounds__(256) void k_gather(const float* __restrict__ emb,
                                                const int* __restrict__ gt,
                                                const float* __restrict__ go,
                                                float* __restrict__ x) {
    int idx = blockIdx.x * 256 + threadIdx.x;     // over B*T*D = 524288
    int d = idx & (DD - 1);
    int t = (idx >> 8) & (TT - 1);
    int b = idx >> 14;
    float v;
    if (t == 0) v = go[d];
    else        v = emb[((size_t)b * NN_ + gt[b * TT + t - 1]) * DD + d];
    x[idx] = v;
}

__global__ __launch_bounds__(256) void k_first_init(int* __restrict__ firstpos) {
    int idx = blockIdx.x * 256 + threadIdx.x;     // B*N
    firstpos[idx] = TT;                            // "never picked"
}

__global__ __launch_bounds__(256) void k_first_min(const int* __restrict__ gt,
                                                   int* __restrict__ firstpos) {
    int idx = blockIdx.x * 256 + threadIdx.x;     // B*T = 2048
    int b = idx / TT;
    int t = idx % TT;
    atomicMin(&firstpos[(size_t)b * NN_ + gt[idx]], t);
}

__global__ __launch_bounds__(64) void k_zero_flags(int* __restrict__ flags) {
    flags[threadIdx.x] = 0;
}

// ---------------- generic tiled f32 GEMMs ----------------
__global__ __launch_bounds__(256) void gemm_nt(const float* __restrict__ A,
                                               const float* __restrict__ Bm,
                                               float* __restrict__ C,
                                               int K, int lda, int ldb, int ldc,
                                               long sA, long sB, long sC,
                                               const float* __restrict__ bias1,
                                               const float* __restrict__ bias2) {
    int bz = blockIdx.z;
    A += (size_t)bz * sA; Bm += (size_t)bz * sB; C += (size_t)bz * sC;
    int tm = blockIdx.y * 64, tn = blockIdx.x * 64;
    __shared__ float As[16][65];
    __shared__ float Bs[16][65];
    int tid = threadIdx.x;
    int tx = tid & 15, ty = tid >> 4;
    float acc[4][4] = {};
    for (int k0 = 0; k0 < K; k0 += 16) {
#pragma unroll
        for (int i = 0; i < 4; ++i) {
            As[tx][ty + 16 * i] = A[(size_t)(tm + ty + 16 * i) * lda + k0 + tx];
            Bs[tx][ty + 16 * i] = Bm[(size_t)(tn + ty + 16 * i) * ldb + k0 + tx];
        }
        __syncthreads();
#pragma unroll
        for (int k = 0; k < 16; ++k) {
            float av[4], bv[4];
#pragma unroll
            for (int i = 0; i < 4; ++i) { av[i] = As[k][ty * 4 + i]; bv[i] = Bs[k][tx * 4 + i]; }
#pragma unroll
            for (int i = 0; i < 4; ++i)
#pragma unroll
                for (int j = 0; j < 4; ++j) acc[i][j] += av[i] * bv[j];
        }
        __syncthreads();
    }
#pragma unroll
    for (int i = 0; i < 4; ++i) {
        int m = tm + ty * 4 + i;
#pragma unroll
        for (int j = 0; j < 4; ++j) {
            int n = tn + tx * 4 + j;
            float v = acc[i][j];
            if (bias1) v += bias1[n];
            if (bias2) v += bias2[n];
            C[(size_t)m * ldc + n] = v;
        }
    }
}

__global__ __launch_bounds__(256) void gemm_nn(const float* __restrict__ A,
                                               const float* __restrict__ Bm,
                                               float* __restrict__ C,
                                               int K, int lda, int ldb, int ldc,
                                               long sA, long sB, long sC) {
    int bz = blockIdx.z;
    A += (size_t)bz * sA; Bm += (size_t)bz * sB; C += (size_t)bz * sC;
    int tm = blockIdx.y * 64, tn = blockIdx.x * 64;
    __shared__ float As[16][65];
    __shared__ float Bs[16][65];
    int tid = threadIdx.x;
    int tx = tid & 15, ty = tid >> 4;
    float acc[4][4] = {};
    for (int k0 = 0; k0 < K; k0 += 16) {
#pragma unroll
        for (int i = 0; i < 4; ++i)
            As[tx][ty + 16 * i] = A[(size_t)(tm + ty + 16 * i) * lda + k0 + tx];
#pragma unroll
        for (int i = 0; i < 4; ++i)
            Bs[(tid >> 6) + 4 * i][tid & 63] =
                Bm[(size_t)(k0 + (tid >> 6) + 4 * i) * ldb + tn + (tid & 63)];
        __syncthreads();
#pragma unroll
        for (int k = 0; k < 16; ++k) {
            float av[4], bv[4];
#pragma unroll
            for (int i = 0; i < 4; ++i) { av[i] = As[k][ty * 4 + i]; bv[i] = Bs[k][tx * 4 + i]; }
#pragma unroll
            for (int i = 0; i < 4; ++i)
#pragma unroll
                for (int j = 0; j < 4; ++j) acc[i][j] += av[i] * bv[j];
        }
        __syncthreads();
    }
#pragma unroll
    for (int i = 0; i < 4; ++i) {
        int m = tm + ty * 4 + i;
#pragma unroll
        for (int j = 0; j < 4; ++j)
            C[(size_t)m * ldc + (tn + tx * 4 + j)] = acc[i][j];
    }
}

__global__ __launch_bounds__(256) void gemm_score(const float* __restrict__ A,   // feat [T,257]
                                                  const float* __restrict__ Bm,  // emb  [N,256]
                                                  float* __restrict__ C,         // out  [T,N]
                                                  const int* __restrict__ firstpos,
                                                  const float* __restrict__ emb_mask,
                                                  int lda, int ldb, int ldc,
                                                  long sA, long sB, long sC) {
    int b = blockIdx.z;
    A += (size_t)b * sA; Bm += (size_t)b * sB; C += (size_t)b * sC;
    int tn = blockIdx.x * 64;
    __shared__ float As[16][65];
    __shared__ float Bs[16][65];
    int tid = threadIdx.x;
    int tx = tid & 15, ty = tid >> 4;
    float acc[4][4] = {};
    for (int k0 = 0; k0 < DD; k0 += 16) {
#pragma unroll
        for (int i = 0; i < 4; ++i) {
            As[tx][ty + 16 * i] = A[(size_t)(ty + 16 * i) * lda + k0 + tx];
            Bs[tx][ty + 16 * i] = Bm[(size_t)(tn + ty + 16 * i) * ldb + k0 + tx];
        }
        __syncthreads();
#pragma unroll
        for (int k = 0; k < 16; ++k) {
            float av[4], bv[4];
#pragma unroll
            for (int i = 0; i < 4; ++i) { av[i] = As[k][ty * 4 + i]; bv[i] = Bs[k][tx * 4 + i]; }
#pragma unroll
            for (int i = 0; i < 4; ++i)
#pragma unroll
                for (int j = 0; j < 4; ++j) acc[i][j] += av[i] * bv[j];
        }
        __syncthreads();
    }
#pragma unroll
    for (int i = 0; i < 4; ++i) {
        int t = ty * 4 + i;
        float fs = A[(size_t)t * lda + 256];   // feat[..., -1]
#pragma unroll
        for (int j = 0; j < 4; ++j) {
            int n = tn + tx * 4 + j;
            float v = acc[i][j];
            if (firstpos[(size_t)b * NN_ + n] < t) v += fs;
            v -= (1.0f - emb_mask[(size_t)b * NN_ + n]) * 1e20f;
            C[(size_t)t * ldc + n] = v;
        }
    }
}

// ---------------- LSTM: 32 cooperating blocks, register-resident weights ----
// Sync protocol: NO bulk cache maintenance. Producers publish h via
// write-through agent-scope relaxed atomic stores (straight to coherent
// point), drain vmcnt, then relaxed agent atomicAdd on flags[t]. Consumers
// poll flags with relaxed agent loads and read hbuf with relaxed agent b64
// atomic loads (cache-bypassing).
__global__ __launch_bounds__(256) void k_lstm_mfma(const float* __restrict__ xW,
                                                   const float* __restrict__ Whh,
                                                   float* __restrict__ hs,
                                                   unsigned short* __restrict__ hbuf,
                                                   int* __restrict__ flags) {
    int p = blockIdx.x;            // 0..31 col-slice
    int tid = threadIdx.x;
    int lane = tid & 63;
    int wid = tid >> 6;            // 4 waves
    int m = wid & 1;               // M-tile (batches 16m..16m+15)
    int n = wid >> 1;              // N-tile (cols 16n..16n+15)

    // ---- persistent weight B-frags: bfrag[kt], lane holds col=16n+(lane&15),
    //      k = kt*32 + (lane>>4)*8 + e
    short8 bfrag[8];
    {
        int col = n * 16 + (lane & 15);        // 0..31
        int g = col >> 3, jj = col & 7;
        const float* wrow = Whh + (size_t)(g * 256 + p * 8 + jj) * DD;
#pragma unroll
        for (int kt = 0; kt < 8; ++kt) {
            short8 f;
#pragma unroll
            for (int e = 0; e < 8; ++e)
                f[e] = (short)f2bf(wrow[kt * 32 + (lane >> 4) * 8 + e]);
            bfrag[kt] = f;
        }
    }

    int ab = tid >> 3;             // activation thread: batch 0..31
    int aj = tid & 7;              // hidden unit jj 0..7
    int j = p * 8 + aj;
    float cstate = 0.0f;

    __shared__ float preact[32][33];

    for (int t = 0; t < TT; ++t) {
        // xW gate biases (independent of flags — issue early, in flight
        // during the spin-wait)
        const float* g0 = xW + ((size_t)ab * TT + t) * GG;
        float xi = g0[j], xf = g0[256 + j], xg = g0[512 + j], xo = g0[768 + j];

        f32x4 acc = {0.f, 0.f, 0.f, 0.f};
        if (t > 0) {
            if (tid == 0) {
                while (__hip_atomic_load(&flags[t - 1], __ATOMIC_RELAXED,
                                         __HIP_MEMORY_SCOPE_AGENT) < LP) { }
            }
            __syncthreads();
            const unsigned long long* hb64 = (const unsigned long long*)
                ((const short*)hbuf + ((size_t)(t - 1) * 2 + m) * 4096);
#pragma unroll
            for (int kt = 0; kt < 8; ++kt) {
                unsigned long long lo = __hip_atomic_load(&hb64[(kt * 64 + lane) * 2 + 0],
                    __ATOMIC_RELAXED, __HIP_MEMORY_SCOPE_AGENT);
                unsigned long long hi = __hip_atomic_load(&hb64[(kt * 64 + lane) * 2 + 1],
                    __ATOMIC_RELAXED, __HIP_MEMORY_SCOPE_AGENT);
                union { unsigned long long q[2]; short8 s; } u;
                u.q[0] = lo; u.q[1] = hi;
                acc = __builtin_amdgcn_mfma_f32_16x16x32_bf16(u.s, bfrag[kt], acc, 0, 0, 0);
            }
        }
        // stage preacts: C layout col=lane&15, row=(lane>>4)*4+r
#pragma unroll
        for (int r = 0; r < 4; ++r)
            preact[16 * m + (lane >> 4) * 4 + r][n * 16 + (lane & 15)] = acc[r];
        __syncthreads();

        // activation: thread (ab, aj)
        float pi = xi + preact[ab][aj];
        float pf = xf + preact[ab][8 + aj];
        float pg = xg + preact[ab][16 + aj];
        float po = xo + preact[ab][24 + aj];
        float ig = 1.0f / (1.0f + __expf(-pi));
        float fg = 1.0f / (1.0f + __expf(-pf));
        float gg = tanhf(pg);
        float og = 1.0f / (1.0f + __expf(-po));
        cstate = fg * cstate + ig * gg;
        float hn = og * tanhf(cstate);

        hs[((size_t)ab * TT + t) * DD + j] = hn;

        if (t < TT - 1) {
            // publish h in A-frag layout, write-through, paired as u32
            float hnb = __shfl_down(hn, 1);
            if ((aj & 1) == 0) {
                unsigned int wv = (unsigned int)f2bf(hn) |
                                  ((unsigned int)f2bf(hnb) << 16);
                size_t idx = ((size_t)t * 2 + (ab >> 4)) * 4096 +
                             (size_t)(p >> 2) * 512 +
                             ((size_t)((p & 3) * 16 + (ab & 15))) * 8 + aj;
                __hip_atomic_store((unsigned int*)&hbuf[idx], wv,
                                   __ATOMIC_RELAXED, __HIP_MEMORY_SCOPE_AGENT);
            }
            asm volatile("s_waitcnt vmcnt(0)" ::: "memory");
        }
        __syncthreads();           // preact reuse + all publishes drained
        if (tid == 0 && t < TT - 1)
            __hip_atomic_fetch_add(&flags[t], 1, __ATOMIC_RELAXED,
                                   __HIP_MEMORY_SCOPE_AGENT);
    }
}

// ---------------- softmax over S (in place, masked) ----------------
__global__ __launch_bounds__(256) void k_softmax(float* __restrict__ raw,
                                                 const float* __restrict__ enc_mask) {
    int bt = blockIdx.x;
    int b = bt / TT;
    float* r = raw + (size_t)bt * SS;
    __shared__ float row[SS];
    __shared__ float red[16];
    int tid = threadIdx.x;
    float mx = -1e30f;
    for (int s = tid; s < SS; s += 256) {
        float v = r[s] - (1.0f - enc_mask[(size_t)b * SS + s]) * 1e20f;
        row[s] = v;
        mx = fmaxf(mx, v);
    }
#pragma unroll
    for (int o = 32; o > 0; o >>= 1) mx = fmaxf(mx, __shfl_down(mx, o));
    if ((tid & 63) == 0) red[tid >> 6] = mx;
    __syncthreads();
    if (tid == 0) {
        float m2 = red[0];
        for (int i = 1; i < 4; ++i) m2 = fmaxf(m2, red[i]);
        red[0] = m2;
    }
    __syncthreads();
    mx = red[0];
    float sum = 0.0f;
    for (int s = tid; s < SS; s += 256) {
        float e = expf(row[s] - mx);
        row[s] = e;
        sum += e;
    }
#pragma unroll
    for (int o = 32; o > 0; o >>= 1) sum += __shfl_down(sum, o);
    if ((tid & 63) == 0) red[8 + (tid >> 6)] = sum;
    __syncthreads();
    if (tid == 0) {
        float s = red[8];
        for (int i = 1; i < 4; ++i) s += red[8 + i];
        red[8] = s;
    }
    __syncthreads();
    float inv = 1.0f / red[8];
    for (int s = tid; s < SS; s += 256) r[s] = row[s] * inv;
}

// ---------------- feat = [hs|attn] @ Wf^T + bf ----------------
__global__ __launch_bounds__(256) void k_feat(const float* __restrict__ hs,
                                              const float* __restrict__ attn,
                                              const float* __restrict__ Wf,
                                              const float* __restrict__ bf,
                                              float* __restrict__ feat) {
    int bt = blockIdx.x;
    __shared__ float cat[2 * DD];
    int tid = threadIdx.x;
    cat[tid] = hs[(size_t)bt * DD + tid];
    cat[DD + tid] = attn[(size_t)bt * DD + tid];
    __syncthreads();
    for (int nn = tid; nn < DD + 1; nn += 256) {
        float s = bf[nn];
        const float* w = Wf + (size_t)nn * (2 * DD);
#pragma unroll 4
        for (int k = 0; k < 2 * DD; ++k) s += cat[k] * w[k];
        feat[(size_t)bt * 257 + nn] = s;
    }
}

// ---------------- launch ----------------
extern "C" void kernel_launch(void* const* d_in, const int* in_sizes, int n_in,
                              void* d_out, int out_size, void* d_ws, size_t ws_size,
                              hipStream_t stream) {
    const float* emb      = (const float*)d_in[0];
    const float* emb_mask = (const float*)d_in[1];
    const float* enc      = (const float*)d_in[2];
    const float* enc_mask = (const float*)d_in[3];
    const int*   gt       = (const int*)d_in[4];
    const float* go       = (const float*)d_in[5];
    const float* Wih      = (const float*)d_in[6];
    const float* Whh      = (const float*)d_in[7];
    const float* bih      = (const float*)d_in[8];
    const float* bhh      = (const float*)d_in[9];
    const float* Wdt      = (const float*)d_in[10];
    const float* bdt      = (const float*)d_in[11];
    const float* Wf       = (const float*)d_in[12];
    const float* bf       = (const float*)d_in[13];
    float* out = (float*)d_out;

    float* ws    = (float*)d_ws;
    float* x     = ws;                                   // [B*T*D]
    float* xW    = x     + (size_t)BB * TT * DD;         // [B*T*G]
    float* hs    = xW    + (size_t)BB * TT * GG;         // [B*T*D]
    float* dec   = hs    + (size_t)BB * TT * DD;         // [B*T*D]
    float* w     = dec   + (size_t)BB * TT * DD;         // [B*T*S]
    float* attn  = w     + (size_t)BB * TT * SS;         // [B*T*D]
    float* feat  = attn  + (size_t)BB * TT * DD;         // [B*T*257]
    float* feat_end = feat + (size_t)BB * TT * 257;
    int* firstpos = (int*)feat_end;                      // [B*N]
    int* flags    = firstpos + (size_t)BB * NN_;         // [T]
    unsigned short* hbuf = (unsigned short*)(flags + 64);// [T*2*8*64*8] bf16 (1MB)

    k_gather<<<BB * TT * DD / 256, 256, 0, stream>>>(emb, gt, go, x);
    k_first_init<<<BB * NN_ / 256, 256, 0, stream>>>(firstpos);
    k_first_min<<<BB * TT / 256, 256, 0, stream>>>(gt, firstpos);
    k_zero_flags<<<1, 64, 0, stream>>>(flags);

    // xW = x @ Wih^T + bih + bhh : [2048,1024]
    gemm_nt<<<dim3(GG / 64, BB * TT / 64, 1), 256, 0, stream>>>(
        x, Wih, xW, DD, DD, DD, GG, 0, 0, 0, bih, bhh);

    k_lstm_mfma<<<LP, 256, 0, stream>>>(xW, Whh, hs, hbuf, flags);

    // dec = hs @ Wdt^T + bdt : [2048,256]
    gemm_nt<<<dim3(DD / 64, BB * TT / 64, 1), 256, 0, stream>>>(
        hs, Wdt, dec, DD, DD, DD, DD, 0, 0, 0, bdt, nullptr);

    // raw[b] = dec[b] @ enc[b]^T : [64,2048], batch 32
    gemm_nt<<<dim3(SS / 64, TT / 64, BB), 256, 0, stream>>>(
        dec, enc, w, DD, DD, DD, SS,
        (long)TT * DD, (long)SS * DD, (long)TT * SS, nullptr, nullptr);

    k_softmax<<<BB * TT, 256, 0, stream>>>(w, enc_mask);

    // attn[b] = w[b] @ enc[b] : [64,256], batch 32
    gemm_nn<<<dim3(DD / 64, TT / 64, BB), 256, 0, stream>>>(
        w, enc, attn, SS, SS, DD, DD,
        (long)TT * SS, (long)SS * DD, (long)TT * DD);

    k_feat<<<BB * TT, 256, 0, stream>>>(hs, attn, Wf, bf, feat);

    // score[b] = feat[b,:, :256] @ emb[b]^T (+ picked, mask)
    gemm_score<<<dim3(NN_ / 64, TT / 64, BB), 256, 0, stream>>>(
        feat, emb, out, firstpos, emb_mask,
        257, DD, NN_, (long)TT * 257, (long)NN_ * DD, (long)TT * NN_);
}

// Round 4
// 462.319 us; speedup vs baseline: 2.2299x; 1.5624x over previous
//
#include <hip/hip_runtime.h>
#include <cstddef>

#define BB 32
#define TT 64
#define NN_ 2048
#define SS 2048
#define DD 256
#define GG 1024
#define LP 32   // LSTM blocks (col-slices)
#define FLD 264 // padded feat leading dim (16B-aligned rows, >=258)

typedef __attribute__((ext_vector_type(8))) short short8;
typedef __attribute__((ext_vector_type(4))) float f32x4;

static __device__ inline unsigned short f2bf(float f) {
    union { float f; unsigned int u; } v; v.f = f;
    unsigned int u = v.u;
    unsigned int r = u + 0x7FFF + ((u >> 16) & 1);   // RNE
    return (unsigned short)(r >> 16);
}

static __device__ inline short8 pack8(float4 a, float4 b) {
    short8 s;
    s[0] = (short)f2bf(a.x); s[1] = (short)f2bf(a.y);
    s[2] = (short)f2bf(a.z); s[3] = (short)f2bf(a.w);
    s[4] = (short)f2bf(b.x); s[5] = (short)f2bf(b.y);
    s[6] = (short)f2bf(b.z); s[7] = (short)f2bf(b.w);
    return s;
}

// ---------------- prep kernels ----------------

__global__ __launch_bounds__(256) void k_gather(const float* __restrict__ emb,
                                                const int* __restrict__ gt,
                                                const float* __restrict__ go,
                                                float* __restrict__ x) {
    int idx = blockIdx.x * 256 + threadIdx.x;     // over B*T*D = 524288
    int d = idx & (DD - 1);
    int t = (idx >> 8) & (TT - 1);
    int b = idx >> 14;
    float v;
    if (t == 0) v = go[d];
    else        v = emb[((size_t)b * NN_ + gt[b * TT + t - 1]) * DD + d];
    x[idx] = v;
}

__global__ __launch_bounds__(256) void k_first_init(int* __restrict__ firstpos) {
    int idx = blockIdx.x * 256 + threadIdx.x;     // B*N
    firstpos[idx] = TT;                            // "never picked"
}

__global__ __launch_bounds__(256) void k_first_min(const int* __restrict__ gt,
                                                   int* __restrict__ firstpos) {
    int idx = blockIdx.x * 256 + threadIdx.x;     // B*T = 2048
    int b = idx / TT;
    int t = idx % TT;
    atomicMin(&firstpos[(size_t)b * NN_ + gt[idx]], t);
}

__global__ __launch_bounds__(64) void k_zero_flags(int* __restrict__ flags) {
    flags[threadIdx.x] = 0;
}

// cat = [hs | attn] : [B*T, 512]
__global__ __launch_bounds__(256) void k_cat(const float* __restrict__ hs,
                                             const float* __restrict__ attn,
                                             float* __restrict__ cat) {
    int idx = blockIdx.x * 256 + threadIdx.x;     // over B*T*512
    int d = idx & 511;
    int bt = idx >> 9;
    cat[idx] = (d < DD) ? hs[(size_t)bt * DD + d]
                        : attn[(size_t)bt * DD + (d - DD)];
}

// ---------------- bf16 MFMA NT GEMM ----------------
// C[m,n] = sum_k A[m*lda+k]*B[n*ldb+k]  (+bias1[n]+bias2[n])
// optional pointer-score epilogue (firstpos/emb_mask/fscol).
// tile 64x64, BK=64, 4 waves as 2x2 of 32x32 (each 2x2 mfma 16x16x32).
__global__ __launch_bounds__(256) void gemm_bf16_nt(
        const float* __restrict__ A, const float* __restrict__ Bm,
        float* __restrict__ C, int K, int lda, int ldb, int ldc,
        long sA, long sB, long sC, int Nlim,
        const float* __restrict__ bias1, const float* __restrict__ bias2,
        const int* __restrict__ firstpos, const float* __restrict__ emb_mask,
        int fscol) {
    int bz = blockIdx.z;
    A += (size_t)bz * sA; Bm += (size_t)bz * sB; C += (size_t)bz * sC;
    int tm = blockIdx.y * 64, tn = blockIdx.x * 64;
    __shared__ short Ab[64][72];
    __shared__ short Bb[64][72];
    __shared__ float sfs[64];
    int tid = threadIdx.x, lane = tid & 63, wid = tid >> 6;
    int wm = wid & 1, wn = wid >> 1;   // wave -> 32x32 quadrant

    if (fscol >= 0 && tid < 64) sfs[tid] = A[(size_t)(tm + tid) * lda + fscol];

    f32x4 zero = {0.f, 0.f, 0.f, 0.f};
    f32x4 acc[2][2] = {{zero, zero}, {zero, zero}};

    int row = tid >> 2, kk = (tid & 3) * 16;
    int brow = tn + row; if (brow >= Nlim) brow = Nlim - 1;
    const float* ap = &A[(size_t)(tm + row) * lda + kk];
    const float* bp = &Bm[(size_t)brow * ldb + kk];

    for (int k0 = 0; k0 < K; k0 += 64) {
        float4 a0 = *(const float4*)(ap + k0);
        float4 a1 = *(const float4*)(ap + k0 + 4);
        float4 a2 = *(const float4*)(ap + k0 + 8);
        float4 a3 = *(const float4*)(ap + k0 + 12);
        float4 b0 = *(const float4*)(bp + k0);
        float4 b1 = *(const float4*)(bp + k0 + 4);
        float4 b2 = *(const float4*)(bp + k0 + 8);
        float4 b3 = *(const float4*)(bp + k0 + 12);
        *(short8*)&Ab[row][kk]     = pack8(a0, a1);
        *(short8*)&Ab[row][kk + 8] = pack8(a2, a3);
        *(short8*)&Bb[row][kk]     = pack8(b0, b1);
        *(short8*)&Bb[row][kk + 8] = pack8(b2, b3);
        __syncthreads();
#pragma unroll
        for (int kt = 0; kt < 2; ++kt) {
            int k8 = kt * 32 + (lane >> 4) * 8;
            short8 fa0 = *(const short8*)&Ab[wm * 32 + (lane & 15)][k8];
            short8 fa1 = *(const short8*)&Ab[wm * 32 + 16 + (lane & 15)][k8];
            short8 fb0 = *(const short8*)&Bb[wn * 32 + (lane & 15)][k8];
            short8 fb1 = *(const short8*)&Bb[wn * 32 + 16 + (lane & 15)][k8];
            acc[0][0] = __builtin_amdgcn_mfma_f32_16x16x32_bf16(fa0, fb0, acc[0][0], 0, 0, 0);
            acc[0][1] = __builtin_amdgcn_mfma_f32_16x16x32_bf16(fa0, fb1, acc[0][1], 0, 0, 0);
            acc[1][0] = __builtin_amdgcn_mfma_f32_16x16x32_bf16(fa1, fb0, acc[1][0], 0, 0, 0);
            acc[1][1] = __builtin_amdgcn_mfma_f32_16x16x32_bf16(fa1, fb1, acc[1][1], 0, 0, 0);
        }
        __syncthreads();
    }

#pragma unroll
    for (int i = 0; i < 2; ++i) {
#pragma unroll
        for (int j = 0; j < 2; ++j) {
#pragma unroll
            for (int r = 0; r < 4; ++r) {
                int lrow = wm * 32 + i * 16 + (lane >> 4) * 4 + r;
                int gcol = tn + wn * 32 + j * 16 + (lane & 15);
                if (gcol < Nlim) {
                    float v = acc[i][j][r];
                    if (bias1) v += bias1[gcol];
                    if (bias2) v += bias2[gcol];
                    if (firstpos) {
                        int grow = tm + lrow;
                        if (firstpos[(size_t)bz * NN_ + gcol] < grow) v += sfs[lrow];
                        v -= (1.0f - emb_mask[(size_t)bz * NN_ + gcol]) * 1e20f;
                    }
                    C[(size_t)(tm + lrow) * ldc + gcol] = v;
                }
            }
        }
    }
}

// ---------------- f32 NN GEMM (attn = w @ enc) ----------------
__global__ __launch_bounds__(256) void gemm_nn(const float* __restrict__ A,
                                               const float* __restrict__ Bm,
                                               float* __restrict__ C,
                                               int K, int lda, int ldb, int ldc,
                                               long sA, long sB, long sC) {
    int bz = blockIdx.z;
    A += (size_t)bz * sA; Bm += (size_t)bz * sB; C += (size_t)bz * sC;
    int tm = blockIdx.y * 64, tn = blockIdx.x * 64;
    __shared__ float As[16][65];
    __shared__ float Bs[16][65];
    int tid = threadIdx.x;
    int tx = tid & 15, ty = tid >> 4;
    float acc[4][4] = {};
    for (int k0 = 0; k0 < K; k0 += 16) {
#pragma unroll
        for (int i = 0; i < 4; ++i)
            As[tx][ty + 16 * i] = A[(size_t)(tm + ty + 16 * i) * lda + k0 + tx];
#pragma unroll
        for (int i = 0; i < 4; ++i)
            Bs[(tid >> 6) + 4 * i][tid & 63] =
                Bm[(size_t)(k0 + (tid >> 6) + 4 * i) * ldb + tn + (tid & 63)];
        __syncthreads();
#pragma unroll
        for (int k = 0; k < 16; ++k) {
            float av[4], bv[4];
#pragma unroll
            for (int i = 0; i < 4; ++i) { av[i] = As[k][ty * 4 + i]; bv[i] = Bs[k][tx * 4 + i]; }
#pragma unroll
            for (int i = 0; i < 4; ++i)
#pragma unroll
                for (int j = 0; j < 4; ++j) acc[i][j] += av[i] * bv[j];
        }
        __syncthreads();
    }
#pragma unroll
    for (int i = 0; i < 4; ++i) {
        int m = tm + ty * 4 + i;
#pragma unroll
        for (int j = 0; j < 4; ++j)
            C[(size_t)m * ldc + (tn + tx * 4 + j)] = acc[i][j];
    }
}

// ---------------- LSTM: 32 cooperating blocks, register-resident weights ----
__global__ __launch_bounds__(256) void k_lstm_mfma(const float* __restrict__ xW,
                                                   const float* __restrict__ Whh,
                                                   float* __restrict__ hs,
                                                   unsigned short* __restrict__ hbuf,
                                                   int* __restrict__ flags) {
    int p = blockIdx.x;            // 0..31 col-slice
    int tid = threadIdx.x;
    int lane = tid & 63;
    int wid = tid >> 6;            // 4 waves
    int m = wid & 1;               // M-tile (batches 16m..16m+15)
    int n = wid >> 1;              // N-tile (cols 16n..16n+15)

    short8 bfrag[8];
    {
        int col = n * 16 + (lane & 15);        // 0..31
        int g = col >> 3, jj = col & 7;
        const float* wrow = Whh + (size_t)(g * 256 + p * 8 + jj) * DD;
#pragma unroll
        for (int kt = 0; kt < 8; ++kt) {
            short8 f;
#pragma unroll
            for (int e = 0; e < 8; ++e)
                f[e] = (short)f2bf(wrow[kt * 32 + (lane >> 4) * 8 + e]);
            bfrag[kt] = f;
        }
    }

    int ab = tid >> 3;             // activation thread: batch 0..31
    int aj = tid & 7;              // hidden unit jj 0..7
    int j = p * 8 + aj;
    float cstate = 0.0f;

    __shared__ float preact[32][33];

    for (int t = 0; t < TT; ++t) {
        const float* g0 = xW + ((size_t)ab * TT + t) * GG;
        float xi = g0[j], xf = g0[256 + j], xg = g0[512 + j], xo = g0[768 + j];

        f32x4 acc = {0.f, 0.f, 0.f, 0.f};
        if (t > 0) {
            if (tid == 0) {
                while (__hip_atomic_load(&flags[t - 1], __ATOMIC_RELAXED,
                                         __HIP_MEMORY_SCOPE_AGENT) < LP) { }
            }
            __syncthreads();
            const unsigned long long* hb64 = (const unsigned long long*)
                ((const short*)hbuf + ((size_t)(t - 1) * 2 + m) * 4096);
#pragma unroll
            for (int kt = 0; kt < 8; ++kt) {
                unsigned long long lo = __hip_atomic_load(&hb64[(kt * 64 + lane) * 2 + 0],
                    __ATOMIC_RELAXED, __HIP_MEMORY_SCOPE_AGENT);
                unsigned long long hi = __hip_atomic_load(&hb64[(kt * 64 + lane) * 2 + 1],
                    __ATOMIC_RELAXED, __HIP_MEMORY_SCOPE_AGENT);
                union { unsigned long long q[2]; short8 s; } u;
                u.q[0] = lo; u.q[1] = hi;
                acc = __builtin_amdgcn_mfma_f32_16x16x32_bf16(u.s, bfrag[kt], acc, 0, 0, 0);
            }
        }
#pragma unroll
        for (int r = 0; r < 4; ++r)
            preact[16 * m + (lane >> 4) * 4 + r][n * 16 + (lane & 15)] = acc[r];
        __syncthreads();

        float pi = xi + preact[ab][aj];
        float pf = xf + preact[ab][8 + aj];
        float pg = xg + preact[ab][16 + aj];
        float po = xo + preact[ab][24 + aj];
        float ig = 1.0f / (1.0f + __expf(-pi));
        float fg = 1.0f / (1.0f + __expf(-pf));
        float gg = tanhf(pg);
        float og = 1.0f / (1.0f + __expf(-po));
        cstate = fg * cstate + ig * gg;
        float hn = og * tanhf(cstate);

        hs[((size_t)ab * TT + t) * DD + j] = hn;

        if (t < TT - 1) {
            float hnb = __shfl_down(hn, 1);
            if ((aj & 1) == 0) {
                unsigned int wv = (unsigned int)f2bf(hn) |
                                  ((unsigned int)f2bf(hnb) << 16);
                size_t idx = ((size_t)t * 2 + (ab >> 4)) * 4096 +
                             (size_t)(p >> 2) * 512 +
                             ((size_t)((p & 3) * 16 + (ab & 15))) * 8 + aj;
                __hip_atomic_store((unsigned int*)&hbuf[idx], wv,
                                   __ATOMIC_RELAXED, __HIP_MEMORY_SCOPE_AGENT);
            }
            asm volatile("s_waitcnt vmcnt(0)" ::: "memory");
        }
        __syncthreads();
        if (tid == 0 && t < TT - 1)
            __hip_atomic_fetch_add(&flags[t], 1, __ATOMIC_RELAXED,
                                   __HIP_MEMORY_SCOPE_AGENT);
    }
}

// ---------------- softmax over S (in place, masked) ----------------
__global__ __launch_bounds__(256) void k_softmax(float* __restrict__ raw,
                                                 const float* __restrict__ enc_mask) {
    int bt = blockIdx.x;
    int b = bt / TT;
    float* r = raw + (size_t)bt * SS;
    __shared__ float row[SS];
    __shared__ float red[16];
    int tid = threadIdx.x;
    float mx = -1e30f;
    for (int s = tid; s < SS; s += 256) {
        float v = r[s] - (1.0f - enc_mask[(size_t)b * SS + s]) * 1e20f;
        row[s] = v;
        mx = fmaxf(mx, v);
    }
#pragma unroll
    for (int o = 32; o > 0; o >>= 1) mx = fmaxf(mx, __shfl_down(mx, o));
    if ((tid & 63) == 0) red[tid >> 6] = mx;
    __syncthreads();
    if (tid == 0) {
        float m2 = red[0];
        for (int i = 1; i < 4; ++i) m2 = fmaxf(m2, red[i]);
        red[0] = m2;
    }
    __syncthreads();
    mx = red[0];
    float sum = 0.0f;
    for (int s = tid; s < SS; s += 256) {
        float e = expf(row[s] - mx);
        row[s] = e;
        sum += e;
    }
#pragma unroll
    for (int o = 32; o > 0; o >>= 1) sum += __shfl_down(sum, o);
    if ((tid & 63) == 0) red[8 + (tid >> 6)] = sum;
    __syncthreads();
    if (tid == 0) {
        float s = red[8];
        for (int i = 1; i < 4; ++i) s += red[8 + i];
        red[8] = s;
    }
    __syncthreads();
    float inv = 1.0f / red[8];
    for (int s = tid; s < SS; s += 256) r[s] = row[s] * inv;
}

// ---------------- launch ----------------
extern "C" void kernel_launch(void* const* d_in, const int* in_sizes, int n_in,
                              void* d_out, int out_size, void* d_ws, size_t ws_size,
                              hipStream_t stream) {
    const float* emb      = (const float*)d_in[0];
    const float* emb_mask = (const float*)d_in[1];
    const float* enc      = (const float*)d_in[2];
    const float* enc_mask = (const float*)d_in[3];
    const int*   gt       = (const int*)d_in[4];
    const float* go       = (const float*)d_in[5];
    const float* Wih      = (const float*)d_in[6];
    const float* Whh      = (const float*)d_in[7];
    const float* bih      = (const float*)d_in[8];
    const float* bhh      = (const float*)d_in[9];
    const float* Wdt      = (const float*)d_in[10];
    const float* bdt      = (const float*)d_in[11];
    const float* Wf       = (const float*)d_in[12];
    const float* bf       = (const float*)d_in[13];
    float* out = (float*)d_out;

    float* ws    = (float*)d_ws;
    float* x     = ws;                                   // [B*T*D]
    float* xW    = x     + (size_t)BB * TT * DD;         // [B*T*G]
    float* hs    = xW    + (size_t)BB * TT * GG;         // [B*T*D]
    float* dec   = hs    + (size_t)BB * TT * DD;         // [B*T*D]
    float* w     = dec   + (size_t)BB * TT * DD;         // [B*T*S]
    float* attn  = w     + (size_t)BB * TT * SS;         // [B*T*D]
    float* feat  = attn  + (size_t)BB * TT * DD;         // [B*T*FLD]
    float* cat   = feat  + (size_t)BB * TT * FLD;        // [B*T*512]
    float* cat_end = cat + (size_t)BB * TT * 512;
    int* firstpos = (int*)cat_end;                       // [B*N]
    int* flags    = firstpos + (size_t)BB * NN_;         // [T]
    unsigned short* hbuf = (unsigned short*)(flags + 64);// [T*2*8*64*8] bf16 (1MB)

    k_gather<<<BB * TT * DD / 256, 256, 0, stream>>>(emb, gt, go, x);
    k_first_init<<<BB * NN_ / 256, 256, 0, stream>>>(firstpos);
    k_first_min<<<BB * TT / 256, 256, 0, stream>>>(gt, firstpos);
    k_zero_flags<<<1, 64, 0, stream>>>(flags);

    // xW = x @ Wih^T + bih + bhh : [2048,1024]
    gemm_bf16_nt<<<dim3(GG / 64, BB * TT / 64, 1), 256, 0, stream>>>(
        x, Wih, xW, DD, DD, DD, GG, 0, 0, 0, GG,
        bih, bhh, nullptr, nullptr, -1);

    k_lstm_mfma<<<LP, 256, 0, stream>>>(xW, Whh, hs, hbuf, flags);

    // dec = hs @ Wdt^T + bdt : [2048,256]
    gemm_bf16_nt<<<dim3(DD / 64, BB * TT / 64, 1), 256, 0, stream>>>(
        hs, Wdt, dec, DD, DD, DD, DD, 0, 0, 0, DD,
        bdt, nullptr, nullptr, nullptr, -1);

    // raw[b] = dec[b] @ enc[b]^T : [64,2048], batch 32
    gemm_bf16_nt<<<dim3(SS / 64, 1, BB), 256, 0, stream>>>(
        dec, enc, w, DD, DD, DD, SS,
        (long)TT * DD, (long)SS * DD, (long)TT * SS, SS,
        nullptr, nullptr, nullptr, nullptr, -1);

    k_softmax<<<BB * TT, 256, 0, stream>>>(w, enc_mask);

    // attn[b] = w[b] @ enc[b] : [64,256], batch 32
    gemm_nn<<<dim3(DD / 64, TT / 64, BB), 256, 0, stream>>>(
        w, enc, attn, SS, SS, DD, DD,
        (long)TT * SS, (long)SS * DD, (long)TT * DD);

    // cat = [hs | attn]
    k_cat<<<BB * TT * 512 / 256, 256, 0, stream>>>(hs, attn, cat);

    // feat = cat @ Wf^T + bf : [2048, 257] (ld FLD)
    gemm_bf16_nt<<<dim3(5, BB * TT / 64, 1), 256, 0, stream>>>(
        cat, Wf, feat, 2 * DD, 2 * DD, 2 * DD, FLD, 0, 0, 0, DD + 1,
        bf, nullptr, nullptr, nullptr, -1);

    // score[b] = feat[b,:, :256] @ emb[b]^T (+ picked, mask)
    gemm_bf16_nt<<<dim3(NN_ / 64, 1, BB), 256, 0, stream>>>(
        feat, emb, out, DD, FLD, DD, NN_,
        (long)TT * FLD, (long)NN_ * DD, (long)TT * NN_, NN_,
        nullptr, nullptr, firstpos, emb_mask, 256);
}

// Round 5
// 367.467 us; speedup vs baseline: 2.8054x; 1.2581x over previous
//
#include <hip/hip_runtime.h>
#include <cstddef>

#define BB 32
#define TT 64
#define NN_ 2048
#define SS 2048
#define DD 256
#define GG 1024
#define LP 32   // LSTM blocks (col-slices)
#define FLD 264 // padded feat leading dim (16B-aligned rows, >=258)

typedef __attribute__((ext_vector_type(8))) short short8;
typedef __attribute__((ext_vector_type(4))) float f32x4;

static __device__ inline unsigned short f2bf(float f) {
    union { float f; unsigned int u; } v; v.f = f;
    unsigned int u = v.u;
    unsigned int r = u + 0x7FFF + ((u >> 16) & 1);   // RNE
    return (unsigned short)(r >> 16);
}

static __device__ inline short8 pack8(float4 a, float4 b) {
    short8 s;
    s[0] = (short)f2bf(a.x); s[1] = (short)f2bf(a.y);
    s[2] = (short)f2bf(a.z); s[3] = (short)f2bf(a.w);
    s[4] = (short)f2bf(b.x); s[5] = (short)f2bf(b.y);
    s[6] = (short)f2bf(b.z); s[7] = (short)f2bf(b.w);
    return s;
}

// true iff no 16-bit half of v equals 0x7F80 (bf16 +inf sentinel)
static __device__ inline bool ok16(unsigned long long v) {
    unsigned long long x = v ^ 0x7F807F807F807F80ULL;
    return (((x - 0x0001000100010001ULL) & ~x & 0x8000800080008000ULL) == 0ULL);
}

// ---------------- prep kernels ----------------

__global__ __launch_bounds__(256) void k_gather(const float* __restrict__ emb,
                                                const int* __restrict__ gt,
                                                const float* __restrict__ go,
                                                float* __restrict__ x) {
    int idx = blockIdx.x * 256 + threadIdx.x;     // over B*T*D = 524288
    int d = idx & (DD - 1);
    int t = (idx >> 8) & (TT - 1);
    int b = idx >> 14;
    float v;
    if (t == 0) v = go[d];
    else        v = emb[((size_t)b * NN_ + gt[b * TT + t - 1]) * DD + d];
    x[idx] = v;
}

__global__ __launch_bounds__(256) void k_first_init(int* __restrict__ firstpos) {
    int idx = blockIdx.x * 256 + threadIdx.x;     // B*N
    firstpos[idx] = TT;                            // "never picked"
}

__global__ __launch_bounds__(256) void k_first_min(const int* __restrict__ gt,
                                                   int* __restrict__ firstpos) {
    int idx = blockIdx.x * 256 + threadIdx.x;     // B*T = 2048
    int b = idx / TT;
    int t = idx % TT;
    atomicMin(&firstpos[(size_t)b * NN_ + gt[idx]], t);
}

__global__ __launch_bounds__(256) void k_poison(unsigned int* __restrict__ hbuf32) {
    hbuf32[blockIdx.x * 256 + threadIdx.x] = 0x7F807F80u;   // bf16 +inf pair
}

// cat = [hs | attn] : [B*T, 512]
__global__ __launch_bounds__(256) void k_cat(const float* __restrict__ hs,
                                             const float* __restrict__ attn,
                                             float* __restrict__ cat) {
    int idx = blockIdx.x * 256 + threadIdx.x;     // over B*T*512
    int d = idx & 511;
    int bt = idx >> 9;
    cat[idx] = (d < DD) ? hs[(size_t)bt * DD + d]
                        : attn[(size_t)bt * DD + (d - DD)];
}

// ---------------- bf16 MFMA NT GEMM ----------------
// C[m,n] = sum_k A[m*lda+k]*B[n*ldb+k]  (+bias1[n]+bias2[n])
// optional pointer-score epilogue (firstpos/emb_mask/fscol).
// tile 64x64, BK=64, 4 waves as 2x2 of 32x32 (each 2x2 mfma 16x16x32).
__global__ __launch_bounds__(256) void gemm_bf16_nt(
        const float* __restrict__ A, const float* __restrict__ Bm,
        float* __restrict__ C, int K, int lda, int ldb, int ldc,
        long sA, long sB, long sC, int Nlim,
        const float* __restrict__ bias1, const float* __restrict__ bias2,
        const int* __restrict__ firstpos, const float* __restrict__ emb_mask,
        int fscol) {
    int bz = blockIdx.z;
    A += (size_t)bz * sA; Bm += (size_t)bz * sB; C += (size_t)bz * sC;
    int tm = blockIdx.y * 64, tn = blockIdx.x * 64;
    __shared__ short Ab[64][72];
    __shared__ short Bb[64][72];
    __shared__ float sfs[64];
    int tid = threadIdx.x, lane = tid & 63, wid = tid >> 6;
    int wm = wid & 1, wn = wid >> 1;   // wave -> 32x32 quadrant

    if (fscol >= 0 && tid < 64) sfs[tid] = A[(size_t)(tm + tid) * lda + fscol];

    f32x4 zero = {0.f, 0.f, 0.f, 0.f};
    f32x4 acc[2][2] = {{zero, zero}, {zero, zero}};

    int row = tid >> 2, kk = (tid & 3) * 16;
    int brow = tn + row; if (brow >= Nlim) brow = Nlim - 1;
    const float* ap = &A[(size_t)(tm + row) * lda + kk];
    const float* bp = &Bm[(size_t)brow * ldb + kk];

    for (int k0 = 0; k0 < K; k0 += 64) {
        float4 a0 = *(const float4*)(ap + k0);
        float4 a1 = *(const float4*)(ap + k0 + 4);
        float4 a2 = *(const float4*)(ap + k0 + 8);
        float4 a3 = *(const float4*)(ap + k0 + 12);
        float4 b0 = *(const float4*)(bp + k0);
        float4 b1 = *(const float4*)(bp + k0 + 4);
        float4 b2 = *(const float4*)(bp + k0 + 8);
        float4 b3 = *(const float4*)(bp + k0 + 12);
        *(short8*)&Ab[row][kk]     = pack8(a0, a1);
        *(short8*)&Ab[row][kk + 8] = pack8(a2, a3);
        *(short8*)&Bb[row][kk]     = pack8(b0, b1);
        *(short8*)&Bb[row][kk + 8] = pack8(b2, b3);
        __syncthreads();
#pragma unroll
        for (int kt = 0; kt < 2; ++kt) {
            int k8 = kt * 32 + (lane >> 4) * 8;
            short8 fa0 = *(const short8*)&Ab[wm * 32 + (lane & 15)][k8];
            short8 fa1 = *(const short8*)&Ab[wm * 32 + 16 + (lane & 15)][k8];
            short8 fb0 = *(const short8*)&Bb[wn * 32 + (lane & 15)][k8];
            short8 fb1 = *(const short8*)&Bb[wn * 32 + 16 + (lane & 15)][k8];
            acc[0][0] = __builtin_amdgcn_mfma_f32_16x16x32_bf16(fa0, fb0, acc[0][0], 0, 0, 0);
            acc[0][1] = __builtin_amdgcn_mfma_f32_16x16x32_bf16(fa0, fb1, acc[0][1], 0, 0, 0);
            acc[1][0] = __builtin_amdgcn_mfma_f32_16x16x32_bf16(fa1, fb0, acc[1][0], 0, 0, 0);
            acc[1][1] = __builtin_amdgcn_mfma_f32_16x16x32_bf16(fa1, fb1, acc[1][1], 0, 0, 0);
        }
        __syncthreads();
    }

#pragma unroll
    for (int i = 0; i < 2; ++i) {
#pragma unroll
        for (int j = 0; j < 2; ++j) {
#pragma unroll
            for (int r = 0; r < 4; ++r) {
                int lrow = wm * 32 + i * 16 + (lane >> 4) * 4 + r;
                int gcol = tn + wn * 32 + j * 16 + (lane & 15);
                if (gcol < Nlim) {
                    float v = acc[i][j][r];
                    if (bias1) v += bias1[gcol];
                    if (bias2) v += bias2[gcol];
                    if (firstpos) {
                        int grow = tm + lrow;
                        if (firstpos[(size_t)bz * NN_ + gcol] < grow) v += sfs[lrow];
                        v -= (1.0f - emb_mask[(size_t)bz * NN_ + gcol]) * 1e20f;
                    }
                    C[(size_t)(tm + lrow) * ldc + gcol] = v;
                }
            }
        }
    }
}

// ---------------- attn = w @ enc (NN) via MFMA, B transposed at frag-read ----
// C[t,d] = sum_s w[t,s] * enc[s,d].  M=64 (all t), N tile 64 (d), K=S.
__global__ __launch_bounds__(256) void gemm_attn(const float* __restrict__ W,
                                                 const float* __restrict__ enc,
                                                 float* __restrict__ attn) {
    int b = blockIdx.z;
    int tn = blockIdx.x * 64;   // d-tile
    const float* Wb = W + (size_t)b * TT * SS;
    const float* Eb = enc + (size_t)b * SS * DD;
    float* Cb = attn + (size_t)b * TT * DD;
    __shared__ short As[64][72];
    __shared__ float Bs[64][66];
    int tid = threadIdx.x, lane = tid & 63, wid = tid >> 6;
    int wm = wid & 1, wn = wid >> 1;
    f32x4 zero = {0.f, 0.f, 0.f, 0.f};
    f32x4 acc[2][2] = {{zero, zero}, {zero, zero}};
    int row = tid >> 2, kk = (tid & 3) * 16;
    const float* ap = Wb + (size_t)row * SS + kk;        // A row = t, k = s
    const float* bp = Eb + (size_t)row * DD + tn + kk;   // B row = s, col = d

    for (int k0 = 0; k0 < SS; k0 += 64) {
        float4 a0 = *(const float4*)(ap + k0);
        float4 a1 = *(const float4*)(ap + k0 + 4);
        float4 a2 = *(const float4*)(ap + k0 + 8);
        float4 a3 = *(const float4*)(ap + k0 + 12);
        *(short8*)&As[row][kk]     = pack8(a0, a1);
        *(short8*)&As[row][kk + 8] = pack8(a2, a3);
        const float* bq = bp + (size_t)k0 * DD;
#pragma unroll
        for (int i = 0; i < 8; ++i)
            *(float2*)&Bs[row][kk + 2 * i] = *(const float2*)(bq + 2 * i);
        __syncthreads();
#pragma unroll
        for (int kt = 0; kt < 2; ++kt) {
            int k8 = kt * 32 + (lane >> 4) * 8;
            short8 fa0 = *(const short8*)&As[wm * 32 + (lane & 15)][k8];
            short8 fa1 = *(const short8*)&As[wm * 32 + 16 + (lane & 15)][k8];
            short8 fb0, fb1;
#pragma unroll
            for (int e = 0; e < 8; ++e) {
                fb0[e] = (short)f2bf(Bs[k8 + e][wn * 32 + (lane & 15)]);
                fb1[e] = (short)f2bf(Bs[k8 + e][wn * 32 + 16 + (lane & 15)]);
            }
            acc[0][0] = __builtin_amdgcn_mfma_f32_16x16x32_bf16(fa0, fb0, acc[0][0], 0, 0, 0);
            acc[0][1] = __builtin_amdgcn_mfma_f32_16x16x32_bf16(fa0, fb1, acc[0][1], 0, 0, 0);
            acc[1][0] = __builtin_amdgcn_mfma_f32_16x16x32_bf16(fa1, fb0, acc[1][0], 0, 0, 0);
            acc[1][1] = __builtin_amdgcn_mfma_f32_16x16x32_bf16(fa1, fb1, acc[1][1], 0, 0, 0);
        }
        __syncthreads();
    }

#pragma unroll
    for (int i = 0; i < 2; ++i)
#pragma unroll
        for (int j = 0; j < 2; ++j)
#pragma unroll
            for (int r = 0; r < 4; ++r) {
                int lrow = wm * 32 + i * 16 + (lane >> 4) * 4 + r;
                int gcol = tn + wn * 32 + j * 16 + (lane & 15);
                Cb[(size_t)lrow * DD + gcol] = acc[i][j][r];
            }
}

// ---------------- LSTM: 32 cooperating blocks, register-resident weights ----
// Flagless sync: h values are in (-1,1), so bf16 0x7F80 (+inf) is an
// impossible value. hbuf is poisoned to the sentinel before launch;
// producers store data words directly (relaxed agent atomics, no fence,
// no drain); consumers poll their own 16 data words until sentinel-free.
__global__ __launch_bounds__(256) void k_lstm_mfma(const float* __restrict__ xW,
                                                   const float* __restrict__ Whh,
                                                   float* __restrict__ hs,
                                                   unsigned short* __restrict__ hbuf) {
    int p = blockIdx.x;            // 0..31 col-slice
    int tid = threadIdx.x;
    int lane = tid & 63;
    int wid = tid >> 6;            // 4 waves
    int m = wid & 1;               // M-tile (batches 16m..16m+15)
    int n = wid >> 1;              // N-tile (cols 16n..16n+15)

    short8 bfrag[8];
    {
        int col = n * 16 + (lane & 15);        // 0..31
        int g = col >> 3, jj = col & 7;
        const float* wrow = Whh + (size_t)(g * 256 + p * 8 + jj) * DD;
#pragma unroll
        for (int kt = 0; kt < 8; ++kt) {
            short8 f;
#pragma unroll
            for (int e = 0; e < 8; ++e)
                f[e] = (short)f2bf(wrow[kt * 32 + (lane >> 4) * 8 + e]);
            bfrag[kt] = f;
        }
    }

    int ab = tid >> 3;             // activation thread: batch 0..31
    int aj = tid & 7;              // hidden unit jj 0..7
    int j = p * 8 + aj;
    float cstate = 0.0f;

    __shared__ float preact[32][33];

    for (int t = 0; t < TT; ++t) {
        // xW gate biases — issue early, in flight during the poll
        const float* g0 = xW + ((size_t)ab * TT + t) * GG;
        float xi = g0[j], xf = g0[256 + j], xg = g0[512 + j], xo = g0[768 + j];

        f32x4 acc = {0.f, 0.f, 0.f, 0.f};
        if (t > 0) {
            const unsigned long long* hb64 = (const unsigned long long*)
                ((const unsigned short*)hbuf + ((size_t)(t - 1) * 2 + m) * 4096);
            unsigned long long q[16];
            bool ready = false;
            while (!ready) {
                ready = true;
#pragma unroll
                for (int kt = 0; kt < 8; ++kt) {
                    q[2 * kt]     = __hip_atomic_load(&hb64[(kt * 64 + lane) * 2 + 0],
                        __ATOMIC_RELAXED, __HIP_MEMORY_SCOPE_AGENT);
                    q[2 * kt + 1] = __hip_atomic_load(&hb64[(kt * 64 + lane) * 2 + 1],
                        __ATOMIC_RELAXED, __HIP_MEMORY_SCOPE_AGENT);
                }
#pragma unroll
                for (int i = 0; i < 16; ++i) ready = ready && ok16(q[i]);
            }
#pragma unroll
            for (int kt = 0; kt < 8; ++kt) {
                union { unsigned long long w[2]; short8 s; } u;
                u.w[0] = q[2 * kt]; u.w[1] = q[2 * kt + 1];
                acc = __builtin_amdgcn_mfma_f32_16x16x32_bf16(u.s, bfrag[kt], acc, 0, 0, 0);
            }
        }
        // stage preacts: C layout col=lane&15, row=(lane>>4)*4+r
#pragma unroll
        for (int r = 0; r < 4; ++r)
            preact[16 * m + (lane >> 4) * 4 + r][n * 16 + (lane & 15)] = acc[r];
        asm volatile("s_waitcnt lgkmcnt(0)\ns_barrier" ::: "memory");

        float pi = xi + preact[ab][aj];
        float pf = xf + preact[ab][8 + aj];
        float pg = xg + preact[ab][16 + aj];
        float po = xo + preact[ab][24 + aj];
        float ig = 1.0f / (1.0f + __expf(-pi));
        float fg = 1.0f / (1.0f + __expf(-pf));
        float gg = tanhf(pg);
        float og = 1.0f / (1.0f + __expf(-po));
        cstate = fg * cstate + ig * gg;
        float hn = og * tanhf(cstate);

        hs[((size_t)ab * TT + t) * DD + j] = hn;

        if (t < TT - 1) {
            // publish h in A-frag layout (paired u32, atomic, no fence)
            float hnb = __shfl_down(hn, 1);
            if ((aj & 1) == 0) {
                unsigned int wv = (unsigned int)f2bf(hn) |
                                  ((unsigned int)f2bf(hnb) << 16);
                size_t idx = ((size_t)t * 2 + (ab >> 4)) * 4096 +
                             (size_t)(p >> 2) * 512 +
                             ((size_t)((p & 3) * 16 + (ab & 15))) * 8 + aj;
                __hip_atomic_store((unsigned int*)&hbuf[idx], wv,
                                   __ATOMIC_RELAXED, __HIP_MEMORY_SCOPE_AGENT);
            }
        }
        asm volatile("s_waitcnt lgkmcnt(0)\ns_barrier" ::: "memory");
    }
}

// ---------------- softmax over S (in place, masked) ----------------
__global__ __launch_bounds__(256) void k_softmax(float* __restrict__ raw,
                                                 const float* __restrict__ enc_mask) {
    int bt = blockIdx.x;
    int b = bt / TT;
    float* r = raw + (size_t)bt * SS;
    __shared__ float row[SS];
    __shared__ float red[16];
    int tid = threadIdx.x;
    float mx = -1e30f;
    for (int s = tid; s < SS; s += 256) {
        float v = r[s] - (1.0f - enc_mask[(size_t)b * SS + s]) * 1e20f;
        row[s] = v;
        mx = fmaxf(mx, v);
    }
#pragma unroll
    for (int o = 32; o > 0; o >>= 1) mx = fmaxf(mx, __shfl_down(mx, o));
    if ((tid & 63) == 0) red[tid >> 6] = mx;
    __syncthreads();
    if (tid == 0) {
        float m2 = red[0];
        for (int i = 1; i < 4; ++i) m2 = fmaxf(m2, red[i]);
        red[0] = m2;
    }
    __syncthreads();
    mx = red[0];
    float sum = 0.0f;
    for (int s = tid; s < SS; s += 256) {
        float e = expf(row[s] - mx);
        row[s] = e;
        sum += e;
    }
#pragma unroll
    for (int o = 32; o > 0; o >>= 1) sum += __shfl_down(sum, o);
    if ((tid & 63) == 0) red[8 + (tid >> 6)] = sum;
    __syncthreads();
    if (tid == 0) {
        float s = red[8];
        for (int i = 1; i < 4; ++i) s += red[8 + i];
        red[8] = s;
    }
    __syncthreads();
    float inv = 1.0f / red[8];
    for (int s = tid; s < SS; s += 256) r[s] = row[s] * inv;
}

// ---------------- launch ----------------
extern "C" void kernel_launch(void* const* d_in, const int* in_sizes, int n_in,
                              void* d_out, int out_size, void* d_ws, size_t ws_size,
                              hipStream_t stream) {
    const float* emb      = (const float*)d_in[0];
    const float* emb_mask = (const float*)d_in[1];
    const float* enc      = (const float*)d_in[2];
    const float* enc_mask = (const float*)d_in[3];
    const int*   gt       = (const int*)d_in[4];
    const float* go       = (const float*)d_in[5];
    const float* Wih      = (const float*)d_in[6];
    const float* Whh      = (const float*)d_in[7];
    const float* bih      = (const float*)d_in[8];
    const float* bhh      = (const float*)d_in[9];
    const float* Wdt      = (const float*)d_in[10];
    const float* bdt      = (const float*)d_in[11];
    const float* Wf       = (const float*)d_in[12];
    const float* bf       = (const float*)d_in[13];
    float* out = (float*)d_out;

    float* ws    = (float*)d_ws;
    float* x     = ws;                                   // [B*T*D]
    float* xW    = x     + (size_t)BB * TT * DD;         // [B*T*G]
    float* hs    = xW    + (size_t)BB * TT * GG;         // [B*T*D]
    float* dec   = hs    + (size_t)BB * TT * DD;         // [B*T*D]
    float* w     = dec   + (size_t)BB * TT * DD;         // [B*T*S]
    float* attn  = w     + (size_t)BB * TT * SS;         // [B*T*D]
    float* feat  = attn  + (size_t)BB * TT * DD;         // [B*T*FLD]
    float* cat   = feat  + (size_t)BB * TT * FLD;        // [B*T*512]
    float* cat_end = cat + (size_t)BB * TT * 512;
    int* firstpos = (int*)cat_end;                       // [B*N]
    unsigned short* hbuf = (unsigned short*)(firstpos + (size_t)BB * NN_); // [T*2*4096] bf16 (1MB)

    k_gather<<<BB * TT * DD / 256, 256, 0, stream>>>(emb, gt, go, x);
    k_first_init<<<BB * NN_ / 256, 256, 0, stream>>>(firstpos);
    k_first_min<<<BB * TT / 256, 256, 0, stream>>>(gt, firstpos);
    k_poison<<<(TT * 2 * 4096 / 2) / 256, 256, 0, stream>>>((unsigned int*)hbuf);

    // xW = x @ Wih^T + bih + bhh : [2048,1024]
    gemm_bf16_nt<<<dim3(GG / 64, BB * TT / 64, 1), 256, 0, stream>>>(
        x, Wih, xW, DD, DD, DD, GG, 0, 0, 0, GG,
        bih, bhh, nullptr, nullptr, -1);

    k_lstm_mfma<<<LP, 256, 0, stream>>>(xW, Whh, hs, hbuf);

    // dec = hs @ Wdt^T + bdt : [2048,256]
    gemm_bf16_nt<<<dim3(DD / 64, BB * TT / 64, 1), 256, 0, stream>>>(
        hs, Wdt, dec, DD, DD, DD, DD, 0, 0, 0, DD,
        bdt, nullptr, nullptr, nullptr, -1);

    // raw[b] = dec[b] @ enc[b]^T : [64,2048], batch 32
    gemm_bf16_nt<<<dim3(SS / 64, 1, BB), 256, 0, stream>>>(
        dec, enc, w, DD, DD, DD, SS,
        (long)TT * DD, (long)SS * DD, (long)TT * SS, SS,
        nullptr, nullptr, nullptr, nullptr, -1);

    k_softmax<<<BB * TT, 256, 0, stream>>>(w, enc_mask);

    // attn[b] = w[b] @ enc[b] : [64,256], batch 32  (MFMA, inline transpose)
    gemm_attn<<<dim3(DD / 64, 1, BB), 256, 0, stream>>>(w, enc, attn);

    // cat = [hs | attn]
    k_cat<<<BB * TT * 512 / 256, 256, 0, stream>>>(hs, attn, cat);

    // feat = cat @ Wf^T + bf : [2048, 257] (ld FLD)
    gemm_bf16_nt<<<dim3(5, BB * TT / 64, 1), 256, 0, stream>>>(
        cat, Wf, feat, 2 * DD, 2 * DD, 2 * DD, FLD, 0, 0, 0, DD + 1,
        bf, nullptr, nullptr, nullptr, -1);

    // score[b] = feat[b,:, :256] @ emb[b]^T (+ picked, mask)
    gemm_bf16_nt<<<dim3(NN_ / 64, 1, BB), 256, 0, stream>>>(
        feat, emb, out, DD, FLD, DD, NN_,
        (long)TT * FLD, (long)NN_ * DD, (long)TT * NN_, NN_,
        nullptr, nullptr, firstpos, emb_mask, 256);
}

// Round 6
// 308.579 us; speedup vs baseline: 3.3408x; 1.1908x over previous
//
#include <hip/hip_runtime.h>
#include <cstddef>

#define BB 32
#define TT 64
#define NN_ 2048
#define SS 2048
#define DD 256
#define GG 1024
#define LP 32   // LSTM blocks (col-slices)
#define FLD 264 // padded feat leading dim (16B-aligned rows, >=258)

typedef __attribute__((ext_vector_type(8))) short short8;
typedef __attribute__((ext_vector_type(4))) float f32x4;

static __device__ inline unsigned short f2bf(float f) {
    union { float f; unsigned int u; } v; v.f = f;
    unsigned int u = v.u;
    unsigned int r = u + 0x7FFF + ((u >> 16) & 1);   // RNE
    return (unsigned short)(r >> 16);
}

static __device__ inline short8 pack8(float4 a, float4 b) {
    short8 s;
    s[0] = (short)f2bf(a.x); s[1] = (short)f2bf(a.y);
    s[2] = (short)f2bf(a.z); s[3] = (short)f2bf(a.w);
    s[4] = (short)f2bf(b.x); s[5] = (short)f2bf(b.y);
    s[6] = (short)f2bf(b.z); s[7] = (short)f2bf(b.w);
    return s;
}

// true iff neither 16-bit half of v equals 0x7F80 (bf16 +inf sentinel).
// (may also flag the word above a true sentinel — harmless, co-occurs.)
static __device__ inline bool ok32(unsigned int v) {
    unsigned int x = v ^ 0x7F807F80u;
    return (((x - 0x00010001u) & ~x & 0x80008000u) == 0u);
}

// ---------------- prep kernels ----------------

__global__ __launch_bounds__(256) void k_gather(const float* __restrict__ emb,
                                                const int* __restrict__ gt,
                                                const float* __restrict__ go,
                                                float* __restrict__ x) {
    int idx = blockIdx.x * 256 + threadIdx.x;     // over B*T*D = 524288
    int d = idx & (DD - 1);
    int t = (idx >> 8) & (TT - 1);
    int b = idx >> 14;
    float v;
    if (t == 0) v = go[d];
    else        v = emb[((size_t)b * NN_ + gt[b * TT + t - 1]) * DD + d];
    x[idx] = v;
}

__global__ __launch_bounds__(256) void k_first_init(int* __restrict__ firstpos) {
    int idx = blockIdx.x * 256 + threadIdx.x;     // B*N
    firstpos[idx] = TT;                            // "never picked"
}

__global__ __launch_bounds__(256) void k_first_min(const int* __restrict__ gt,
                                                   int* __restrict__ firstpos) {
    int idx = blockIdx.x * 256 + threadIdx.x;     // B*T = 2048
    int b = idx / TT;
    int t = idx % TT;
    atomicMin(&firstpos[(size_t)b * NN_ + gt[idx]], t);
}

__global__ __launch_bounds__(256) void k_poison(unsigned int* __restrict__ hbuf32) {
    hbuf32[blockIdx.x * 256 + threadIdx.x] = 0x7F807F80u;   // bf16 +inf pair
}

// hs[(b*T+t)*256 + j] <- hbuf32[t][j>>1][b]  (bf16 -> f32)
__global__ __launch_bounds__(256) void k_h2f(const unsigned int* __restrict__ hbuf32,
                                             float* __restrict__ hs) {
    int idx = blockIdx.x * 256 + threadIdx.x;     // over B*T*D
    int j = idx & 255;
    int t = (idx >> 8) & 63;
    int b = idx >> 14;
    unsigned int w = hbuf32[(size_t)t * 4096 + (j >> 1) * 32 + b];
    unsigned short h = (j & 1) ? (unsigned short)(w >> 16) : (unsigned short)(w & 0xFFFF);
    union { unsigned int u; float f; } v;
    v.u = ((unsigned int)h) << 16;
    hs[idx] = v.f;
}

// cat = [hs | attn] : [B*T, 512]
__global__ __launch_bounds__(256) void k_cat(const float* __restrict__ hs,
                                             const float* __restrict__ attn,
                                             float* __restrict__ cat) {
    int idx = blockIdx.x * 256 + threadIdx.x;     // over B*T*512
    int d = idx & 511;
    int bt = idx >> 9;
    cat[idx] = (d < DD) ? hs[(size_t)bt * DD + d]
                        : attn[(size_t)bt * DD + (d - DD)];
}

// ---------------- bf16 MFMA NT GEMM ----------------
__global__ __launch_bounds__(256) void gemm_bf16_nt(
        const float* __restrict__ A, const float* __restrict__ Bm,
        float* __restrict__ C, int K, int lda, int ldb, int ldc,
        long sA, long sB, long sC, int Nlim,
        const float* __restrict__ bias1, const float* __restrict__ bias2,
        const int* __restrict__ firstpos, const float* __restrict__ emb_mask,
        int fscol) {
    int bz = blockIdx.z;
    A += (size_t)bz * sA; Bm += (size_t)bz * sB; C += (size_t)bz * sC;
    int tm = blockIdx.y * 64, tn = blockIdx.x * 64;
    __shared__ short Ab[64][72];
    __shared__ short Bb[64][72];
    __shared__ float sfs[64];
    int tid = threadIdx.x, lane = tid & 63, wid = tid >> 6;
    int wm = wid & 1, wn = wid >> 1;   // wave -> 32x32 quadrant

    if (fscol >= 0 && tid < 64) sfs[tid] = A[(size_t)(tm + tid) * lda + fscol];

    f32x4 zero = {0.f, 0.f, 0.f, 0.f};
    f32x4 acc[2][2] = {{zero, zero}, {zero, zero}};

    int row = tid >> 2, kk = (tid & 3) * 16;
    int brow = tn + row; if (brow >= Nlim) brow = Nlim - 1;
    const float* ap = &A[(size_t)(tm + row) * lda + kk];
    const float* bp = &Bm[(size_t)brow * ldb + kk];

    for (int k0 = 0; k0 < K; k0 += 64) {
        float4 a0 = *(const float4*)(ap + k0);
        float4 a1 = *(const float4*)(ap + k0 + 4);
        float4 a2 = *(const float4*)(ap + k0 + 8);
        float4 a3 = *(const float4*)(ap + k0 + 12);
        float4 b0 = *(const float4*)(bp + k0);
        float4 b1 = *(const float4*)(bp + k0 + 4);
        float4 b2 = *(const float4*)(bp + k0 + 8);
        float4 b3 = *(const float4*)(bp + k0 + 12);
        *(short8*)&Ab[row][kk]     = pack8(a0, a1);
        *(short8*)&Ab[row][kk + 8] = pack8(a2, a3);
        *(short8*)&Bb[row][kk]     = pack8(b0, b1);
        *(short8*)&Bb[row][kk + 8] = pack8(b2, b3);
        __syncthreads();
#pragma unroll
        for (int kt = 0; kt < 2; ++kt) {
            int k8 = kt * 32 + (lane >> 4) * 8;
            short8 fa0 = *(const short8*)&Ab[wm * 32 + (lane & 15)][k8];
            short8 fa1 = *(const short8*)&Ab[wm * 32 + 16 + (lane & 15)][k8];
            short8 fb0 = *(const short8*)&Bb[wn * 32 + (lane & 15)][k8];
            short8 fb1 = *(const short8*)&Bb[wn * 32 + 16 + (lane & 15)][k8];
            acc[0][0] = __builtin_amdgcn_mfma_f32_16x16x32_bf16(fa0, fb0, acc[0][0], 0, 0, 0);
            acc[0][1] = __builtin_amdgcn_mfma_f32_16x16x32_bf16(fa0, fb1, acc[0][1], 0, 0, 0);
            acc[1][0] = __builtin_amdgcn_mfma_f32_16x16x32_bf16(fa1, fb0, acc[1][0], 0, 0, 0);
            acc[1][1] = __builtin_amdgcn_mfma_f32_16x16x32_bf16(fa1, fb1, acc[1][1], 0, 0, 0);
        }
        __syncthreads();
    }

#pragma unroll
    for (int i = 0; i < 2; ++i) {
#pragma unroll
        for (int j = 0; j < 2; ++j) {
#pragma unroll
            for (int r = 0; r < 4; ++r) {
                int lrow = wm * 32 + i * 16 + (lane >> 4) * 4 + r;
                int gcol = tn + wn * 32 + j * 16 + (lane & 15);
                if (gcol < Nlim) {
                    float v = acc[i][j][r];
                    if (bias1) v += bias1[gcol];
                    if (bias2) v += bias2[gcol];
                    if (firstpos) {
                        int grow = tm + lrow;
                        if (firstpos[(size_t)bz * NN_ + gcol] < grow) v += sfs[lrow];
                        v -= (1.0f - emb_mask[(size_t)bz * NN_ + gcol]) * 1e20f;
                    }
                    C[(size_t)(tm + lrow) * ldc + gcol] = v;
                }
            }
        }
    }
}

// ---------------- attn = w @ enc (NN) via MFMA, B transposed at frag-read ----
__global__ __launch_bounds__(256) void gemm_attn(const float* __restrict__ W,
                                                 const float* __restrict__ enc,
                                                 float* __restrict__ attn) {
    int b = blockIdx.z;
    int tn = blockIdx.x * 64;   // d-tile
    const float* Wb = W + (size_t)b * TT * SS;
    const float* Eb = enc + (size_t)b * SS * DD;
    float* Cb = attn + (size_t)b * TT * DD;
    __shared__ short As[64][72];
    __shared__ float Bs[64][66];
    int tid = threadIdx.x, lane = tid & 63, wid = tid >> 6;
    int wm = wid & 1, wn = wid >> 1;
    f32x4 zero = {0.f, 0.f, 0.f, 0.f};
    f32x4 acc[2][2] = {{zero, zero}, {zero, zero}};
    int row = tid >> 2, kk = (tid & 3) * 16;
    const float* ap = Wb + (size_t)row * SS + kk;        // A row = t, k = s
    const float* bp = Eb + (size_t)row * DD + tn + kk;   // B row = s, col = d

    for (int k0 = 0; k0 < SS; k0 += 64) {
        float4 a0 = *(const float4*)(ap + k0);
        float4 a1 = *(const float4*)(ap + k0 + 4);
        float4 a2 = *(const float4*)(ap + k0 + 8);
        float4 a3 = *(const float4*)(ap + k0 + 12);
        *(short8*)&As[row][kk]     = pack8(a0, a1);
        *(short8*)&As[row][kk + 8] = pack8(a2, a3);
        const float* bq = bp + (size_t)k0 * DD;
#pragma unroll
        for (int i = 0; i < 8; ++i)
            *(float2*)&Bs[row][kk + 2 * i] = *(const float2*)(bq + 2 * i);
        __syncthreads();
#pragma unroll
        for (int kt = 0; kt < 2; ++kt) {
            int k8 = kt * 32 + (lane >> 4) * 8;
            short8 fa0 = *(const short8*)&As[wm * 32 + (lane & 15)][k8];
            short8 fa1 = *(const short8*)&As[wm * 32 + 16 + (lane & 15)][k8];
            short8 fb0, fb1;
#pragma unroll
            for (int e = 0; e < 8; ++e) {
                fb0[e] = (short)f2bf(Bs[k8 + e][wn * 32 + (lane & 15)]);
                fb1[e] = (short)f2bf(Bs[k8 + e][wn * 32 + 16 + (lane & 15)]);
            }
            acc[0][0] = __builtin_amdgcn_mfma_f32_16x16x32_bf16(fa0, fb0, acc[0][0], 0, 0, 0);
            acc[0][1] = __builtin_amdgcn_mfma_f32_16x16x32_bf16(fa0, fb1, acc[0][1], 0, 0, 0);
            acc[1][0] = __builtin_amdgcn_mfma_f32_16x16x32_bf16(fa1, fb0, acc[1][0], 0, 0, 0);
            acc[1][1] = __builtin_amdgcn_mfma_f32_16x16x32_bf16(fa1, fb1, acc[1][1], 0, 0, 0);
        }
        __syncthreads();
    }

#pragma unroll
    for (int i = 0; i < 2; ++i)
#pragma unroll
        for (int j = 0; j < 2; ++j)
#pragma unroll
            for (int r = 0; r < 4; ++r) {
                int lrow = wm * 32 + i * 16 + (lane >> 4) * 4 + r;
                int gcol = tn + wn * 32 + j * 16 + (lane & 15);
                Cb[(size_t)lrow * DD + gcol] = acc[i][j][r];
            }
}

// ---------------- LSTM v3: transposed MFMA, in-lane activation -------------
// Block p owns 8 hidden units j = p*8..p*8+7. Wave (mi,ni) computes
// preact^T [16 rows = 4 units x 4 gates][16 batches] = Wslice^T (A) x h (B).
// A-frag row rr = jj*4 + g  ->  C row (lane>>4)*4 + r gives lane = (jj,b)
// holding all 4 gate preacts in acc[0..3]: activation fully in-lane.
// h published as paired-bf16 u32 agent atomics into hbuf32[t][j>>1][b];
// consumers poll the data words (sentinel 0x7F80) -- no flags, no barriers.
__global__ __launch_bounds__(256) void k_lstm_mfma(const float* __restrict__ xW,
                                                   const float* __restrict__ Whh,
                                                   unsigned int* __restrict__ hbuf32) {
    int p = blockIdx.x;            // 0..31 col-slice
    int tid = threadIdx.x;
    int lane = tid & 63;
    int wid = tid >> 6;            // 4 waves
    int mi = wid & 1;              // unit-halves (4 units each)
    int ni = wid >> 1;             // batch-halves (16 batches each)
    int jj = lane >> 4;            // 0..3 unit within mi-group
    int bl = lane & 15;            // batch within ni-group
    int j = p * 8 + mi * 4 + jj;   // hidden unit this lane activates
    int b = ni * 16 + bl;          // batch this lane activates

    // persistent weight A-frags: row rr=lane&15 -> (g = rr&3, jw = rr>>2)
    short8 afrag[8];
    {
        int rr = lane & 15;
        const float* wrow = Whh + (size_t)((rr & 3) * 256 + p * 8 + mi * 4 + (rr >> 2)) * DD;
#pragma unroll
        for (int kt = 0; kt < 8; ++kt) {
            short8 f;
#pragma unroll
            for (int e = 0; e < 8; ++e)
                f[e] = (short)f2bf(wrow[kt * 32 + (lane >> 4) * 8 + e]);
            afrag[kt] = f;
        }
    }

    float cstate = 0.0f;
    const int wb = jj * 128 + b;   // word base: (jj*4 + w4)*32 + b

    for (int t = 0; t < TT; ++t) {
        // xW gate biases for (b, j) -- issue before the poll
        const float* g0 = xW + ((size_t)b * TT + t) * GG + j;
        float xb0 = g0[0], xb1 = g0[256], xb2 = g0[512], xb3 = g0[768];

        f32x4 acc = {0.f, 0.f, 0.f, 0.f};
        if (t > 0) {
            const unsigned int* hb = hbuf32 + (size_t)(t - 1) * 4096;
            unsigned int q[32];
            bool ready = false;
            while (!ready) {
                ready = true;
#pragma unroll
                for (int kt = 0; kt < 8; ++kt)
#pragma unroll
                    for (int w4 = 0; w4 < 4; ++w4)
                        q[kt * 4 + w4] = __hip_atomic_load(&hb[kt * 512 + wb + w4 * 32],
                            __ATOMIC_RELAXED, __HIP_MEMORY_SCOPE_AGENT);
#pragma unroll
                for (int i = 0; i < 32; ++i) ready = ready && ok32(q[i]);
            }
#pragma unroll
            for (int kt = 0; kt < 8; ++kt) {
                union { unsigned int w[4]; short8 s; } u;
                u.w[0] = q[kt * 4 + 0]; u.w[1] = q[kt * 4 + 1];
                u.w[2] = q[kt * 4 + 2]; u.w[3] = q[kt * 4 + 3];
                acc = __builtin_amdgcn_mfma_f32_16x16x32_bf16(afrag[kt], u.s, acc, 0, 0, 0);
            }
        }

        float pi = xb0 + acc[0];
        float pf = xb1 + acc[1];
        float pg = xb2 + acc[2];
        float po = xb3 + acc[3];
        float ig = 1.0f / (1.0f + __expf(-pi));
        float fg = 1.0f / (1.0f + __expf(-pf));
        float gg = tanhf(pg);
        float og = 1.0f / (1.0f + __expf(-po));
        cstate = fg * cstate + ig * gg;
        float hn = og * tanhf(cstate);

        // publish (j, j+1) pair for batch b
        float hnb = __shfl_down(hn, 16);
        if ((jj & 1) == 0) {
            unsigned int wv = (unsigned int)f2bf(hn) |
                              ((unsigned int)f2bf(hnb) << 16);
            __hip_atomic_store(&hbuf32[(size_t)t * 4096 +
                                       (p * 4 + mi * 2 + (jj >> 1)) * 32 + b],
                               wv, __ATOMIC_RELAXED, __HIP_MEMORY_SCOPE_AGENT);
        }
        // drain promptly so stores don't queue behind next step's polls
        asm volatile("s_waitcnt vmcnt(0)" ::: "memory");
    }
}

// ---------------- softmax over S (in place, masked) ----------------
__global__ __launch_bounds__(256) void k_softmax(float* __restrict__ raw,
                                                 const float* __restrict__ enc_mask) {
    int bt = blockIdx.x;
    int b = bt / TT;
    float* r = raw + (size_t)bt * SS;
    __shared__ float row[SS];
    __shared__ float red[16];
    int tid = threadIdx.x;
    float mx = -1e30f;
    for (int s = tid; s < SS; s += 256) {
        float v = r[s] - (1.0f - enc_mask[(size_t)b * SS + s]) * 1e20f;
        row[s] = v;
        mx = fmaxf(mx, v);
    }
#pragma unroll
    for (int o = 32; o > 0; o >>= 1) mx = fmaxf(mx, __shfl_down(mx, o));
    if ((tid & 63) == 0) red[tid >> 6] = mx;
    __syncthreads();
    if (tid == 0) {
        float m2 = red[0];
        for (int i = 1; i < 4; ++i) m2 = fmaxf(m2, red[i]);
        red[0] = m2;
    }
    __syncthreads();
    mx = red[0];
    float sum = 0.0f;
    for (int s = tid; s < SS; s += 256) {
        float e = expf(row[s] - mx);
        row[s] = e;
        sum += e;
    }
#pragma unroll
    for (int o = 32; o > 0; o >>= 1) sum += __shfl_down(sum, o);
    if ((tid & 63) == 0) red[8 + (tid >> 6)] = sum;
    __syncthreads();
    if (tid == 0) {
        float s = red[8];
        for (int i = 1; i < 4; ++i) s += red[8 + i];
        red[8] = s;
    }
    __syncthreads();
    float inv = 1.0f / red[8];
    for (int s = tid; s < SS; s += 256) r[s] = row[s] * inv;
}

// ---------------- launch ----------------
extern "C" void kernel_launch(void* const* d_in, const int* in_sizes, int n_in,
                              void* d_out, int out_size, void* d_ws, size_t ws_size,
                              hipStream_t stream) {
    const float* emb      = (const float*)d_in[0];
    const float* emb_mask = (const float*)d_in[1];
    const float* enc      = (const float*)d_in[2];
    const float* enc_mask = (const float*)d_in[3];
    const int*   gt       = (const int*)d_in[4];
    const float* go       = (const float*)d_in[5];
    const float* Wih      = (const float*)d_in[6];
    const float* Whh      = (const float*)d_in[7];
    const float* bih      = (const float*)d_in[8];
    const float* bhh      = (const float*)d_in[9];
    const float* Wdt      = (const float*)d_in[10];
    const float* bdt      = (const float*)d_in[11];
    const float* Wf       = (const float*)d_in[12];
    const float* bf       = (const float*)d_in[13];
    float* out = (float*)d_out;

    float* ws    = (float*)d_ws;
    float* x     = ws;                                   // [B*T*D]
    float* xW    = x     + (size_t)BB * TT * DD;         // [B*T*G]
    float* hs    = xW    + (size_t)BB * TT * GG;         // [B*T*D]
    float* dec   = hs    + (size_t)BB * TT * DD;         // [B*T*D]
    float* w     = dec   + (size_t)BB * TT * DD;         // [B*T*S]
    float* attn  = w     + (size_t)BB * TT * SS;         // [B*T*D]
    float* feat  = attn  + (size_t)BB * TT * DD;         // [B*T*FLD]
    float* cat   = feat  + (size_t)BB * TT * FLD;        // [B*T*512]
    float* cat_end = cat + (size_t)BB * TT * 512;
    int* firstpos = (int*)cat_end;                       // [B*N]
    unsigned int* hbuf32 = (unsigned int*)(firstpos + (size_t)BB * NN_); // [T*128*32] u32 (1MB)

    k_gather<<<BB * TT * DD / 256, 256, 0, stream>>>(emb, gt, go, x);
    k_first_init<<<BB * NN_ / 256, 256, 0, stream>>>(firstpos);
    k_first_min<<<BB * TT / 256, 256, 0, stream>>>(gt, firstpos);
    k_poison<<<TT * 128 * 32 / 256, 256, 0, stream>>>(hbuf32);

    // xW = x @ Wih^T + bih + bhh : [2048,1024]
    gemm_bf16_nt<<<dim3(GG / 64, BB * TT / 64, 1), 256, 0, stream>>>(
        x, Wih, xW, DD, DD, DD, GG, 0, 0, 0, GG,
        bih, bhh, nullptr, nullptr, -1);

    k_lstm_mfma<<<LP, 256, 0, stream>>>(xW, Whh, hbuf32);

    // hs (f32) from hbuf (bf16)
    k_h2f<<<BB * TT * DD / 256, 256, 0, stream>>>(hbuf32, hs);

    // dec = hs @ Wdt^T + bdt : [2048,256]
    gemm_bf16_nt<<<dim3(DD / 64, BB * TT / 64, 1), 256, 0, stream>>>(
        hs, Wdt, dec, DD, DD, DD, DD, 0, 0, 0, DD,
        bdt, nullptr, nullptr, nullptr, -1);

    // raw[b] = dec[b] @ enc[b]^T : [64,2048], batch 32
    gemm_bf16_nt<<<dim3(SS / 64, 1, BB), 256, 0, stream>>>(
        dec, enc, w, DD, DD, DD, SS,
        (long)TT * DD, (long)SS * DD, (long)TT * SS, SS,
        nullptr, nullptr, nullptr, nullptr, -1);

    k_softmax<<<BB * TT, 256, 0, stream>>>(w, enc_mask);

    // attn[b] = w[b] @ enc[b] : [64,256], batch 32  (MFMA, inline transpose)
    gemm_attn<<<dim3(DD / 64, 1, BB), 256, 0, stream>>>(w, enc, attn);

    // cat = [hs | attn]
    k_cat<<<BB * TT * 512 / 256, 256, 0, stream>>>(hs, attn, cat);

    // feat = cat @ Wf^T + bf : [2048, 257] (ld FLD)
    gemm_bf16_nt<<<dim3(5, BB * TT / 64, 1), 256, 0, stream>>>(
        cat, Wf, feat, 2 * DD, 2 * DD, 2 * DD, FLD, 0, 0, 0, DD + 1,
        bf, nullptr, nullptr, nullptr, -1);

    // score[b] = feat[b,:, :256] @ emb[b]^T (+ picked, mask)
    gemm_bf16_nt<<<dim3(NN_ / 64, 1, BB), 256, 0, stream>>>(
        feat, emb, out, DD, FLD, DD, NN_,
        (long)TT * FLD, (long)NN_ * DD, (long)TT * NN_, NN_,
        nullptr, nullptr, firstpos, emb_mask, 256);
}